// Round 1
// baseline (1123.678 us; speedup 1.0000x reference)
//
#include <hip/hip_runtime.h>
#include <math.h>

// Problem constants
#define Bb 4
#define Lc 2048
#define Dm 512
#define Ei 1024     // E = 2*D_MODEL
#define Ns 16       // d_state
#define Rr 32       // dt_rank
#define EPSf 1e-5f

__device__ __forceinline__ float siluf(float x) {
    return x / (1.f + __expf(-x));
}
__device__ __forceinline__ float softplusf(float x) {
    return x > 20.f ? x : log1pf(__expf(x));
}

// ---------------------------------------------------------------------------
// K1: per-row LayerNorm stats (mu, rstd). One wave per row, 4 rows per block.
// ---------------------------------------------------------------------------
__global__ __launch_bounds__(256) void k_ln_stats(const float* __restrict__ inp,
                                                  float* __restrict__ stats) {
    int row  = blockIdx.x * 4 + (threadIdx.x >> 6);
    int lane = threadIdx.x & 63;
    const float4* p = (const float4*)(inp + (size_t)row * Dm);
    float4 v0 = p[lane];
    float4 v1 = p[lane + 64];
    float s = v0.x + v0.y + v0.z + v0.w + v1.x + v1.y + v1.z + v1.w;
    float q = v0.x * v0.x + v0.y * v0.y + v0.z * v0.z + v0.w * v0.w +
              v1.x * v1.x + v1.y * v1.y + v1.z * v1.z + v1.w * v1.w;
#pragma unroll
    for (int off = 32; off >= 1; off >>= 1) {
        s += __shfl_xor(s, off);
        q += __shfl_xor(q, off);
    }
    if (lane == 0) {
        float mu  = s * (1.f / Dm);
        float var = q * (1.f / Dm) - mu * mu;
        stats[(size_t)row * 2]     = mu;
        stats[(size_t)row * 2 + 1] = rsqrtf(var + EPSf);
    }
}

// ---------------------------------------------------------------------------
// K2: in_proj GEMM with fused LayerNorm on the B operand.
// xz[b][m][n] = sum_d LN(inp[b][n][d]) * W[m][d];  M=2048 (2E), N=L, K=512
// Tile 128x128, BK=16, 256 threads, 8x8 micro-tile (split 4+4).
// ---------------------------------------------------------------------------
__global__ __launch_bounds__(256) void k_gemm_inproj(
    const float* __restrict__ W,     // (2048,512)
    const float* __restrict__ inp,   // (4,2048,512)
    const float* __restrict__ stats, // (4*2048,2)
    const float* __restrict__ nw, const float* __restrict__ nb,
    float* __restrict__ xz)          // (4,2048,2048)
{
    const int b  = blockIdx.z;
    const int m0 = blockIdx.x * 128;
    const int n0 = blockIdx.y * 128;
    __shared__ float As[16][132];
    __shared__ float Bs[16][132];
    const int tid = threadIdx.x;
    const int tm = tid >> 4, tn = tid & 15;
    const int lr  = tid >> 2;         // 0..63
    const int lc4 = (tid & 3) * 4;    // 0,4,8,12

    float acc[8][8];
#pragma unroll
    for (int i = 0; i < 8; i++)
#pragma unroll
        for (int j = 0; j < 8; j++) acc[i][j] = 0.f;

    const float* inpb = inp + (size_t)b * Lc * Dm;
    const float* stb  = stats + (size_t)b * Lc * 2;

    for (int k0 = 0; k0 < Dm; k0 += 16) {
        // A tile (W): 128 m x 16 k
#pragma unroll
        for (int half = 0; half < 2; half++) {
            int m = lr + half * 64;
            float4 v = *(const float4*)&W[(size_t)(m0 + m) * Dm + k0 + lc4];
            As[lc4 + 0][m] = v.x; As[lc4 + 1][m] = v.y;
            As[lc4 + 2][m] = v.z; As[lc4 + 3][m] = v.w;
        }
        // B tile (LN(inp)): 128 n x 16 k
        float w0 = nw[k0 + lc4], w1 = nw[k0 + lc4 + 1], w2 = nw[k0 + lc4 + 2], w3 = nw[k0 + lc4 + 3];
        float c0 = nb[k0 + lc4], c1 = nb[k0 + lc4 + 1], c2 = nb[k0 + lc4 + 2], c3 = nb[k0 + lc4 + 3];
#pragma unroll
        for (int half = 0; half < 2; half++) {
            int n = lr + half * 64;
            float mu = stb[2 * (n0 + n)], rs = stb[2 * (n0 + n) + 1];
            float4 v = *(const float4*)&inpb[(size_t)(n0 + n) * Dm + k0 + lc4];
            Bs[lc4 + 0][n] = (v.x - mu) * rs * w0 + c0;
            Bs[lc4 + 1][n] = (v.y - mu) * rs * w1 + c1;
            Bs[lc4 + 2][n] = (v.z - mu) * rs * w2 + c2;
            Bs[lc4 + 3][n] = (v.w - mu) * rs * w3 + c3;
        }
        __syncthreads();
#pragma unroll
        for (int kk = 0; kk < 16; kk++) {
            float a[8], bv[8];
            *(float4*)&a[0]  = *(const float4*)&As[kk][tm * 4];
            *(float4*)&a[4]  = *(const float4*)&As[kk][tm * 4 + 64];
            *(float4*)&bv[0] = *(const float4*)&Bs[kk][tn * 4];
            *(float4*)&bv[4] = *(const float4*)&Bs[kk][tn * 4 + 64];
#pragma unroll
            for (int i = 0; i < 8; i++)
#pragma unroll
                for (int j = 0; j < 8; j++) acc[i][j] += a[i] * bv[j];
        }
        __syncthreads();
    }
    float* Cb = xz + (size_t)b * 2048 * Lc;
#pragma unroll
    for (int i = 0; i < 8; i++) {
        int m = m0 + (i < 4 ? tm * 4 + i : 64 + tm * 4 + (i - 4));
#pragma unroll
        for (int jh = 0; jh < 2; jh++) {
            int n = n0 + (jh == 0 ? tn * 4 : 64 + tn * 4);
            float4 v = make_float4(acc[i][jh * 4 + 0], acc[i][jh * 4 + 1],
                                   acc[i][jh * 4 + 2], acc[i][jh * 4 + 3]);
            *(float4*)&Cb[(size_t)m * Lc + n] = v;
        }
    }
}

// ---------------------------------------------------------------------------
// K3: causal depthwise conv (K=4) + SiLU.  rev=1 reads time-reversed input.
// xc[b][e][l] = silu(bias[e] + sum_i w[e][i]*x[b][e][sel(l-3+i)])
// ---------------------------------------------------------------------------
__global__ __launch_bounds__(256) void k_conv(const float* __restrict__ xz,
                                              const float* __restrict__ cw,
                                              const float* __restrict__ cb,
                                              float* __restrict__ xc, int rev) {
    size_t idx = (size_t)blockIdx.x * 256 + threadIdx.x;  // < B*E*L
    int l = (int)(idx & (Lc - 1));
    size_t ce = idx >> 11;
    int e = (int)(ce & (Ei - 1));
    int b = (int)(ce >> 10);
    const float* x = xz + ((size_t)b * 2048 + e) * Lc;
    float w0 = cw[e * 4], w1 = cw[e * 4 + 1], w2 = cw[e * 4 + 2], w3 = cw[e * 4 + 3];
    float acc = cb[e];
    float wv[4] = {w0, w1, w2, w3};
#pragma unroll
    for (int i = 0; i < 4; i++) {
        int j = l - 3 + i;
        if (j >= 0) acc += wv[i] * x[rev ? (Lc - 1 - j) : j];
    }
    xc[((size_t)b * Ei + e) * Lc + l] = siluf(acc);
}

// ---------------------------------------------------------------------------
// K4: x_proj GEMM: xdbl[b][m][n] = sum_e xc[b][e][n] * xpw[m][e]
// M=64, N=L, K=E=1024.  Tile 64x128, BK=16, 256 threads, 4x8 micro-tile.
// ---------------------------------------------------------------------------
__global__ __launch_bounds__(256) void k_gemm_xdbl(
    const float* __restrict__ xpw,  // (64,1024)
    const float* __restrict__ xc,   // (4,1024,2048)
    float* __restrict__ xdbl)       // (4,64,2048)
{
    const int b  = blockIdx.z;
    const int n0 = blockIdx.y * 128;
    __shared__ float As[16][68];
    __shared__ float Bs[16][132];
    const int tid = threadIdx.x;
    const int tm = tid >> 4, tn = tid & 15;
    const int lr  = tid >> 2;
    const int lc4 = (tid & 3) * 4;
    const int n4 = (tid & 31) * 4;
    const int kr = tid >> 5;  // 0..7

    float acc[4][8];
#pragma unroll
    for (int i = 0; i < 4; i++)
#pragma unroll
        for (int j = 0; j < 8; j++) acc[i][j] = 0.f;

    const float* xcb = xc + (size_t)b * Ei * Lc;

    for (int k0 = 0; k0 < Ei; k0 += 16) {
        // A tile: 64 m x 16 k
        {
            float4 v = *(const float4*)&xpw[(size_t)lr * Ei + k0 + lc4];
            As[lc4 + 0][lr] = v.x; As[lc4 + 1][lr] = v.y;
            As[lc4 + 2][lr] = v.z; As[lc4 + 3][lr] = v.w;
        }
        // B tile: 16 k x 128 n (n-contiguous layout)
#pragma unroll
        for (int kh = 0; kh < 2; kh++) {
            int k = kr + kh * 8;
            float4 v = *(const float4*)&xcb[(size_t)(k0 + k) * Lc + n0 + n4];
            *(float4*)&Bs[k][n4] = v;
        }
        __syncthreads();
#pragma unroll
        for (int kk = 0; kk < 16; kk++) {
            float a[4], bv[8];
            *(float4*)&a[0]  = *(const float4*)&As[kk][tm * 4];
            *(float4*)&bv[0] = *(const float4*)&Bs[kk][tn * 4];
            *(float4*)&bv[4] = *(const float4*)&Bs[kk][tn * 4 + 64];
#pragma unroll
            for (int i = 0; i < 4; i++)
#pragma unroll
                for (int j = 0; j < 8; j++) acc[i][j] += a[i] * bv[j];
        }
        __syncthreads();
    }
    float* xd = xdbl + (size_t)b * 64 * Lc;
#pragma unroll
    for (int i = 0; i < 4; i++) {
        int m = tm * 4 + i;
        *(float4*)&xd[(size_t)m * Lc + n0 + tn * 4] =
            make_float4(acc[i][0], acc[i][1], acc[i][2], acc[i][3]);
        *(float4*)&xd[(size_t)m * Lc + n0 + 64 + tn * 4] =
            make_float4(acc[i][4], acc[i][5], acc[i][6], acc[i][7]);
    }
}

// ---------------------------------------------------------------------------
// K5: selective scan. 16 lanes per channel (one per state n), 16 channels per
// block, all channels of a block share b (so B/C LDS stages are shared).
// dt_proj + softplus fused (32-FMA dot from LDS-staged dt_low).
// rev=1: consume reversed sequence, write gated output to reversed position.
// accum=1: += into y (second branch).
// ---------------------------------------------------------------------------
__global__ __launch_bounds__(256) void k_scan(
    const float* __restrict__ xc,    // (4,1024,2048)  u
    const float* __restrict__ xdbl,  // (4,64,2048) rows: 0..31 dt_low, 32..47 B, 48..63 C
    const float* __restrict__ xz,    // (4,2048,2048)  z = rows E..2E-1
    const float* __restrict__ dtw,   // (1024,32)
    const float* __restrict__ dtb,   // (1024)
    const float* __restrict__ Alog,  // (1024,16)
    const float* __restrict__ Dp,    // (1024)
    float* __restrict__ y,           // (4,1024,2048)
    int rev, int accum)
{
    const int bx = blockIdx.x;       // 256 blocks
    const int b  = bx >> 6;          // 64 blocks per batch
    const int e0 = (bx & 63) << 4;
    const int tid = threadIdx.x;
    const int g = tid >> 4;          // channel group 0..15
    const int n = tid & 15;          // state index
    const int e = e0 + g;

    __shared__ float sW[16][33];     // dt_proj_w rows for the block's channels
    __shared__ float sDtl[32][68];   // dt_low chunk
    __shared__ float sU[16][68];
    __shared__ float sDt[16][68];
    __shared__ float sB[16][68];
    __shared__ float sC[16][68];
    __shared__ float sZ[16][68];

    for (int i = tid; i < 512; i += 256)
        sW[i >> 5][i & 31] = dtw[(size_t)(e0 + (i >> 5)) * 32 + (i & 31)];

    const float A_n     = -__expf(Alog[(size_t)e * Ns + n]);
    const float Dv      = Dp[e];
    const float dt_bias = dtb[e];
    float h = 0.f;

    const float* up = xc + ((size_t)b * Ei + e) * Lc;
    const float* zp = xz + ((size_t)b * 2048 + Ei + e) * Lc;
    const float* xdb = xdbl + (size_t)b * 64 * Lc;

    for (int t0 = 0; t0 < Lc; t0 += 64) {
        // ---- stage chunk ----
        *(float4*)&sU[g][n * 4] = *(const float4*)&up[t0 + n * 4];
        *(float4*)&sB[g][n * 4] = *(const float4*)&xdb[(size_t)(32 + g) * Lc + t0 + n * 4];
        *(float4*)&sC[g][n * 4] = *(const float4*)&xdb[(size_t)(48 + g) * Lc + t0 + n * 4];
#pragma unroll
        for (int jj = 0; jj < 4; jj++) {
            int tt = n * 4 + jj;
            int gi = rev ? (Lc - 1 - (t0 + tt)) : (t0 + tt);
            sZ[g][tt] = zp[gi];
        }
#pragma unroll
        for (int f = 0; f < 2; f++) {
            int fi = tid * 2 + f;            // 512 float4 slots
            int row = fi >> 4, c4 = (fi & 15) * 4;
            *(float4*)&sDtl[row][c4] = *(const float4*)&xdb[(size_t)row * Lc + t0 + c4];
        }
        __syncthreads();

        // ---- fused dt_proj + softplus ----
#pragma unroll
        for (int jj = 0; jj < 4; jj++) {
            int tt = n * 4 + jj;
            float a = dt_bias;
#pragma unroll
            for (int r = 0; r < 32; r++) a += sDtl[r][tt] * sW[g][r];
            sDt[g][tt] = softplusf(a);
        }
        __syncthreads();

        // ---- recurrence ----
        float yb[4];
#pragma unroll
        for (int tt = 0; tt < 64; tt++) {
            float dt = sDt[g][tt];
            float dA = __expf(dt * A_n);
            float du = dt * sU[g][tt];
            h = dA * h + du * sB[n][tt];
            float p = h * sC[n][tt];
            p += __shfl_xor(p, 8);
            p += __shfl_xor(p, 4);
            p += __shfl_xor(p, 2);
            p += __shfl_xor(p, 1);
            if (n == (tt & 15)) yb[tt >> 4] = p;
        }

        // ---- gate + write ----
#pragma unroll
        for (int q = 0; q < 4; q++) {
            int tt = q * 16 + n;
            int t  = t0 + tt;
            float val = (yb[q] + Dv * sU[g][tt]) * siluf(sZ[g][tt]);
            size_t idx = ((size_t)b * Ei + e) * Lc + (size_t)(rev ? (Lc - 1 - t) : t);
            if (accum) y[idx] += val;
            else       y[idx] = val;
        }
        __syncthreads();
    }
}

// ---------------------------------------------------------------------------
// K6: out_proj GEMM: out[b][n][m] = sum_e y[b][e][n] * Wout[m][e]
// M=512, N=L, K=1024.  Tile 128x128. Stores transposed (scalar).
// ---------------------------------------------------------------------------
__global__ __launch_bounds__(256) void k_gemm_outproj(
    const float* __restrict__ Wout,  // (512,1024)
    const float* __restrict__ y,     // (4,1024,2048)
    float* __restrict__ out)         // (4,2048,512) pre-norm
{
    const int b  = blockIdx.z;
    const int m0 = blockIdx.x * 128;
    const int n0 = blockIdx.y * 128;
    __shared__ float As[16][132];
    __shared__ float Bs[16][132];
    const int tid = threadIdx.x;
    const int tm = tid >> 4, tn = tid & 15;
    const int lr  = tid >> 2;
    const int lc4 = (tid & 3) * 4;
    const int n4 = (tid & 31) * 4;
    const int kr = tid >> 5;

    float acc[8][8];
#pragma unroll
    for (int i = 0; i < 8; i++)
#pragma unroll
        for (int j = 0; j < 8; j++) acc[i][j] = 0.f;

    const float* yb = y + (size_t)b * Ei * Lc;

    for (int k0 = 0; k0 < Ei; k0 += 16) {
#pragma unroll
        for (int half = 0; half < 2; half++) {
            int m = lr + half * 64;
            float4 v = *(const float4*)&Wout[(size_t)(m0 + m) * Ei + k0 + lc4];
            As[lc4 + 0][m] = v.x; As[lc4 + 1][m] = v.y;
            As[lc4 + 2][m] = v.z; As[lc4 + 3][m] = v.w;
        }
#pragma unroll
        for (int kh = 0; kh < 2; kh++) {
            int k = kr + kh * 8;
            float4 v = *(const float4*)&yb[(size_t)(k0 + k) * Lc + n0 + n4];
            *(float4*)&Bs[k][n4] = v;
        }
        __syncthreads();
#pragma unroll
        for (int kk = 0; kk < 16; kk++) {
            float a[8], bv[8];
            *(float4*)&a[0]  = *(const float4*)&As[kk][tm * 4];
            *(float4*)&a[4]  = *(const float4*)&As[kk][tm * 4 + 64];
            *(float4*)&bv[0] = *(const float4*)&Bs[kk][tn * 4];
            *(float4*)&bv[4] = *(const float4*)&Bs[kk][tn * 4 + 64];
#pragma unroll
            for (int i = 0; i < 8; i++)
#pragma unroll
                for (int j = 0; j < 8; j++) acc[i][j] += a[i] * bv[j];
        }
        __syncthreads();
    }
    float* ob = out + (size_t)b * Lc * Dm;
#pragma unroll
    for (int i = 0; i < 8; i++) {
        int m = m0 + (i < 4 ? tm * 4 + i : 64 + tm * 4 + (i - 4));
#pragma unroll
        for (int j = 0; j < 8; j++) {
            int nn = n0 + (j < 4 ? tn * 4 + j : 64 + tn * 4 + (j - 4));
            ob[(size_t)nn * Dm + m] = acc[i][j];
        }
    }
}

// ---------------------------------------------------------------------------
// K7: fused residual add + RMSNorm (in place on d_out).
// ---------------------------------------------------------------------------
__global__ __launch_bounds__(256) void k_rms(float* __restrict__ out,
                                             const float* __restrict__ resid,
                                             const float* __restrict__ w) {
    int row  = blockIdx.x * 4 + (threadIdx.x >> 6);
    int lane = threadIdx.x & 63;
    float4* po = (float4*)(out + (size_t)row * Dm);
    const float4* pr = (const float4*)(resid + (size_t)row * Dm);
    const float4* pw = (const float4*)w;
    float4 a0 = po[lane], a1 = po[lane + 64];
    float4 r0 = pr[lane], r1 = pr[lane + 64];
    a0.x += r0.x; a0.y += r0.y; a0.z += r0.z; a0.w += r0.w;
    a1.x += r1.x; a1.y += r1.y; a1.z += r1.z; a1.w += r1.w;
    float q = a0.x * a0.x + a0.y * a0.y + a0.z * a0.z + a0.w * a0.w +
              a1.x * a1.x + a1.y * a1.y + a1.z * a1.z + a1.w * a1.w;
#pragma unroll
    for (int off = 32; off >= 1; off >>= 1) q += __shfl_xor(q, off);
    float scale = rsqrtf(q * (1.f / Dm) + EPSf);
    float4 w0 = pw[lane], w1 = pw[lane + 64];
    a0.x *= scale * w0.x; a0.y *= scale * w0.y; a0.z *= scale * w0.z; a0.w *= scale * w0.w;
    a1.x *= scale * w1.x; a1.y *= scale * w1.y; a1.z *= scale * w1.z; a1.w *= scale * w1.w;
    po[lane] = a0;
    po[lane + 64] = a1;
}

// ---------------------------------------------------------------------------
extern "C" void kernel_launch(void* const* d_in, const int* in_sizes, int n_in,
                              void* d_out, int out_size, void* d_ws, size_t ws_size,
                              hipStream_t stream) {
    const float* inp   = (const float*)d_in[0];
    const float* nw    = (const float*)d_in[1];
    const float* nbv   = (const float*)d_in[2];
    const float* Win   = (const float*)d_in[3];
    const float* cwf   = (const float*)d_in[4];
    const float* cbf   = (const float*)d_in[5];
    const float* xpwf  = (const float*)d_in[6];
    const float* dtwf  = (const float*)d_in[7];
    const float* dtbf  = (const float*)d_in[8];
    const float* Alogf = (const float*)d_in[9];
    const float* Df    = (const float*)d_in[10];
    const float* cwr   = (const float*)d_in[11];
    const float* cbr   = (const float*)d_in[12];
    const float* xpwr  = (const float*)d_in[13];
    const float* dtwr  = (const float*)d_in[14];
    const float* dtbr  = (const float*)d_in[15];
    const float* Alogr = (const float*)d_in[16];
    const float* Dr    = (const float*)d_in[17];
    const float* Wout  = (const float*)d_in[18];
    const float* nfw   = (const float*)d_in[19];
    float* outp = (float*)d_out;
    float* ws   = (float*)d_ws;

    float* stats = ws;                                   // 16K floats
    float* xz    = ws + 16384;                           // 4*2048*2048
    float* xc    = xz + (size_t)4 * 2048 * 2048;         // 4*1024*2048
    float* xdbl  = xc + (size_t)4 * 1024 * 2048;         // 4*64*2048
    float* y     = xdbl + (size_t)4 * 64 * 2048;         // 4*1024*2048

    k_ln_stats<<<2048, 256, 0, stream>>>(inp, stats);
    k_gemm_inproj<<<dim3(16, 16, 4), 256, 0, stream>>>(Win, inp, stats, nw, nbv, xz);

    // forward branch
    k_conv<<<(4 * 1024 * 2048) / 256, 256, 0, stream>>>(xz, cwf, cbf, xc, 0);
    k_gemm_xdbl<<<dim3(1, 16, 4), 256, 0, stream>>>(xpwf, xc, xdbl);
    k_scan<<<256, 256, 0, stream>>>(xc, xdbl, xz, dtwf, dtbf, Alogf, Df, y, 0, 0);

    // reverse branch (index-reversed, accumulates into y)
    k_conv<<<(4 * 1024 * 2048) / 256, 256, 0, stream>>>(xz, cwr, cbr, xc, 1);
    k_gemm_xdbl<<<dim3(1, 16, 4), 256, 0, stream>>>(xpwr, xc, xdbl);
    k_scan<<<256, 256, 0, stream>>>(xc, xdbl, xz, dtwr, dtbr, Alogr, Dr, y, 1, 1);

    k_gemm_outproj<<<dim3(4, 16, 4), 256, 0, stream>>>(Wout, y, outp);
    k_rms<<<2048, 256, 0, stream>>>(outp, inp, nfw);
}

// Round 2
// 1053.756 us; speedup vs baseline: 1.0664x; 1.0664x over previous
//
#include <hip/hip_runtime.h>
#include <math.h>

// Problem constants
#define Bb 4
#define Lc 2048
#define Dm 512
#define Ei 1024     // E = 2*D_MODEL
#define Ns 16       // d_state
#define Rr 32       // dt_rank
#define EPSf 1e-5f
#define NCH 8       // scan chunks
#define TCH 256     // timesteps per chunk

__device__ __forceinline__ float siluf(float x) {
    return x / (1.f + __expf(-x));
}
__device__ __forceinline__ float softplusf(float x) {
    return x > 20.f ? x : log1pf(__expf(x));
}

// ---------------------------------------------------------------------------
// K1: per-row LayerNorm stats (mu, rstd). One wave per row, 4 rows per block.
// ---------------------------------------------------------------------------
__global__ __launch_bounds__(256) void k_ln_stats(const float* __restrict__ inp,
                                                  float* __restrict__ stats) {
    int row  = blockIdx.x * 4 + (threadIdx.x >> 6);
    int lane = threadIdx.x & 63;
    const float4* p = (const float4*)(inp + (size_t)row * Dm);
    float4 v0 = p[lane];
    float4 v1 = p[lane + 64];
    float s = v0.x + v0.y + v0.z + v0.w + v1.x + v1.y + v1.z + v1.w;
    float q = v0.x * v0.x + v0.y * v0.y + v0.z * v0.z + v0.w * v0.w +
              v1.x * v1.x + v1.y * v1.y + v1.z * v1.z + v1.w * v1.w;
#pragma unroll
    for (int off = 32; off >= 1; off >>= 1) {
        s += __shfl_xor(s, off);
        q += __shfl_xor(q, off);
    }
    if (lane == 0) {
        float mu  = s * (1.f / Dm);
        float var = q * (1.f / Dm) - mu * mu;
        stats[(size_t)row * 2]     = mu;
        stats[(size_t)row * 2 + 1] = rsqrtf(var + EPSf);
    }
}

// ---------------------------------------------------------------------------
// K2: in_proj GEMM with fused LayerNorm on the B operand.
// xz[b][m][n] = sum_d LN(inp[b][n][d]) * W[m][d];  M=2048 (2E), N=L, K=512
// ---------------------------------------------------------------------------
__global__ __launch_bounds__(256) void k_gemm_inproj(
    const float* __restrict__ W,     // (2048,512)
    const float* __restrict__ inp,   // (4,2048,512)
    const float* __restrict__ stats, // (4*2048,2)
    const float* __restrict__ nw, const float* __restrict__ nb,
    float* __restrict__ xz)          // (4,2048,2048)
{
    const int b  = blockIdx.z;
    const int m0 = blockIdx.x * 128;
    const int n0 = blockIdx.y * 128;
    __shared__ float As[16][132];
    __shared__ float Bs[16][132];
    const int tid = threadIdx.x;
    const int tm = tid >> 4, tn = tid & 15;
    const int lr  = tid >> 2;         // 0..63
    const int lc4 = (tid & 3) * 4;    // 0,4,8,12

    float acc[8][8];
#pragma unroll
    for (int i = 0; i < 8; i++)
#pragma unroll
        for (int j = 0; j < 8; j++) acc[i][j] = 0.f;

    const float* inpb = inp + (size_t)b * Lc * Dm;
    const float* stb  = stats + (size_t)b * Lc * 2;

    for (int k0 = 0; k0 < Dm; k0 += 16) {
#pragma unroll
        for (int half = 0; half < 2; half++) {
            int m = lr + half * 64;
            float4 v = *(const float4*)&W[(size_t)(m0 + m) * Dm + k0 + lc4];
            As[lc4 + 0][m] = v.x; As[lc4 + 1][m] = v.y;
            As[lc4 + 2][m] = v.z; As[lc4 + 3][m] = v.w;
        }
        float w0 = nw[k0 + lc4], w1 = nw[k0 + lc4 + 1], w2 = nw[k0 + lc4 + 2], w3 = nw[k0 + lc4 + 3];
        float c0 = nb[k0 + lc4], c1 = nb[k0 + lc4 + 1], c2 = nb[k0 + lc4 + 2], c3 = nb[k0 + lc4 + 3];
#pragma unroll
        for (int half = 0; half < 2; half++) {
            int n = lr + half * 64;
            float mu = stb[2 * (n0 + n)], rs = stb[2 * (n0 + n) + 1];
            float4 v = *(const float4*)&inpb[(size_t)(n0 + n) * Dm + k0 + lc4];
            Bs[lc4 + 0][n] = (v.x - mu) * rs * w0 + c0;
            Bs[lc4 + 1][n] = (v.y - mu) * rs * w1 + c1;
            Bs[lc4 + 2][n] = (v.z - mu) * rs * w2 + c2;
            Bs[lc4 + 3][n] = (v.w - mu) * rs * w3 + c3;
        }
        __syncthreads();
#pragma unroll
        for (int kk = 0; kk < 16; kk++) {
            float a[8], bv[8];
            *(float4*)&a[0]  = *(const float4*)&As[kk][tm * 4];
            *(float4*)&a[4]  = *(const float4*)&As[kk][tm * 4 + 64];
            *(float4*)&bv[0] = *(const float4*)&Bs[kk][tn * 4];
            *(float4*)&bv[4] = *(const float4*)&Bs[kk][tn * 4 + 64];
#pragma unroll
            for (int i = 0; i < 8; i++)
#pragma unroll
                for (int j = 0; j < 8; j++) acc[i][j] += a[i] * bv[j];
        }
        __syncthreads();
    }
    float* Cb = xz + (size_t)b * 2048 * Lc;
#pragma unroll
    for (int i = 0; i < 8; i++) {
        int m = m0 + (i < 4 ? tm * 4 + i : 64 + tm * 4 + (i - 4));
#pragma unroll
        for (int jh = 0; jh < 2; jh++) {
            int n = n0 + (jh == 0 ? tn * 4 : 64 + tn * 4);
            float4 v = make_float4(acc[i][jh * 4 + 0], acc[i][jh * 4 + 1],
                                   acc[i][jh * 4 + 2], acc[i][jh * 4 + 3]);
            *(float4*)&Cb[(size_t)m * Lc + n] = v;
        }
    }
}

// ---------------------------------------------------------------------------
// K3: causal depthwise conv (K=4) + SiLU.  rev=1 reads time-reversed input.
// ---------------------------------------------------------------------------
__global__ __launch_bounds__(256) void k_conv(const float* __restrict__ xz,
                                              const float* __restrict__ cw,
                                              const float* __restrict__ cb,
                                              float* __restrict__ xc, int rev) {
    size_t idx = (size_t)blockIdx.x * 256 + threadIdx.x;  // < B*E*L
    int l = (int)(idx & (Lc - 1));
    size_t ce = idx >> 11;
    int e = (int)(ce & (Ei - 1));
    int b = (int)(ce >> 10);
    const float* x = xz + ((size_t)b * 2048 + e) * Lc;
    float acc = cb[e];
    float wv[4] = {cw[e * 4], cw[e * 4 + 1], cw[e * 4 + 2], cw[e * 4 + 3]};
#pragma unroll
    for (int i = 0; i < 4; i++) {
        int j = l - 3 + i;
        if (j >= 0) acc += wv[i] * x[rev ? (Lc - 1 - j) : j];
    }
    xc[((size_t)b * Ei + e) * Lc + l] = siluf(acc);
}

// ---------------------------------------------------------------------------
// K4: x_proj GEMM: xdbl[b][m][n] = sum_e xc[b][e][n] * xpw[m][e]
// ---------------------------------------------------------------------------
__global__ __launch_bounds__(256) void k_gemm_xdbl(
    const float* __restrict__ xpw,  // (64,1024)
    const float* __restrict__ xc,   // (4,1024,2048)
    float* __restrict__ xdbl)       // (4,64,2048)
{
    const int b  = blockIdx.z;
    const int n0 = blockIdx.y * 128;
    __shared__ float As[16][68];
    __shared__ float Bs[16][132];
    const int tid = threadIdx.x;
    const int tm = tid >> 4, tn = tid & 15;
    const int lr  = tid >> 2;
    const int lc4 = (tid & 3) * 4;
    const int n4 = (tid & 31) * 4;
    const int kr = tid >> 5;  // 0..7

    float acc[4][8];
#pragma unroll
    for (int i = 0; i < 4; i++)
#pragma unroll
        for (int j = 0; j < 8; j++) acc[i][j] = 0.f;

    const float* xcb = xc + (size_t)b * Ei * Lc;

    for (int k0 = 0; k0 < Ei; k0 += 16) {
        {
            float4 v = *(const float4*)&xpw[(size_t)lr * Ei + k0 + lc4];
            As[lc4 + 0][lr] = v.x; As[lc4 + 1][lr] = v.y;
            As[lc4 + 2][lr] = v.z; As[lc4 + 3][lr] = v.w;
        }
#pragma unroll
        for (int kh = 0; kh < 2; kh++) {
            int k = kr + kh * 8;
            float4 v = *(const float4*)&xcb[(size_t)(k0 + k) * Lc + n0 + n4];
            *(float4*)&Bs[k][n4] = v;
        }
        __syncthreads();
#pragma unroll
        for (int kk = 0; kk < 16; kk++) {
            float a[4], bv[8];
            *(float4*)&a[0]  = *(const float4*)&As[kk][tm * 4];
            *(float4*)&bv[0] = *(const float4*)&Bs[kk][tn * 4];
            *(float4*)&bv[4] = *(const float4*)&Bs[kk][tn * 4 + 64];
#pragma unroll
            for (int i = 0; i < 4; i++)
#pragma unroll
                for (int j = 0; j < 8; j++) acc[i][j] += a[i] * bv[j];
        }
        __syncthreads();
    }
    float* xd = xdbl + (size_t)b * 64 * Lc;
#pragma unroll
    for (int i = 0; i < 4; i++) {
        int m = tm * 4 + i;
        *(float4*)&xd[(size_t)m * Lc + n0 + tn * 4] =
            make_float4(acc[i][0], acc[i][1], acc[i][2], acc[i][3]);
        *(float4*)&xd[(size_t)m * Lc + n0 + 64 + tn * 4] =
            make_float4(acc[i][4], acc[i][5], acc[i][6], acc[i][7]);
    }
}

// ---------------------------------------------------------------------------
// K5a: scan pass 1 — per-chunk affine transform (P = prod dA, S = local h).
// Grid: NCH*256 blocks; block = 16 channels x 16 states.
// dt recomputed from dt_low via 32-FMA dot (fused, not stored).
// ---------------------------------------------------------------------------
__global__ __launch_bounds__(256) void k_scan_p1(
    const float* __restrict__ xc,    // (4,1024,2048)  u
    const float* __restrict__ xdbl,  // (4,64,2048)
    const float* __restrict__ dtw,   // (1024,32)
    const float* __restrict__ dtb,   // (1024)
    const float* __restrict__ Alog,  // (1024,16)
    float* __restrict__ Pbuf,        // [NCH][4][1024][16]
    float* __restrict__ Sbuf)
{
    const int bx = blockIdx.x;
    const int c  = bx >> 8;          // chunk
    const int j  = bx & 255;
    const int b  = j >> 6;
    const int e0 = (j & 63) << 4;
    const int tid = threadIdx.x;
    const int g = tid >> 4;          // channel group 0..15
    const int n = tid & 15;          // state index
    const int e = e0 + g;

    __shared__ float sW[16][33];
    __shared__ float sDtl[32][68];
    __shared__ float sU[16][68];
    __shared__ float sDt[16][68];
    __shared__ float sB[16][68];

    for (int i = tid; i < 512; i += 256)
        sW[i >> 5][i & 31] = dtw[(size_t)(e0 + (i >> 5)) * 32 + (i & 31)];

    const float A_n     = -__expf(Alog[(size_t)e * Ns + n]);
    const float dt_bias = dtb[e];
    float h = 0.f, Pa = 1.f;

    const float* up  = xc + ((size_t)b * Ei + e) * Lc;
    const float* xdb = xdbl + (size_t)b * 64 * Lc;

    const int tbeg = c * TCH;
    for (int t0 = tbeg; t0 < tbeg + TCH; t0 += 64) {
        *(float4*)&sU[g][n * 4] = *(const float4*)&up[t0 + n * 4];
        *(float4*)&sB[g][n * 4] = *(const float4*)&xdb[(size_t)(32 + g) * Lc + t0 + n * 4];
#pragma unroll
        for (int f = 0; f < 2; f++) {
            int fi = tid * 2 + f;
            int row = fi >> 4, c4 = (fi & 15) * 4;
            *(float4*)&sDtl[row][c4] = *(const float4*)&xdb[(size_t)row * Lc + t0 + c4];
        }
        __syncthreads();
#pragma unroll
        for (int jj = 0; jj < 4; jj++) {
            int tt = n * 4 + jj;
            float a = dt_bias;
#pragma unroll
            for (int r = 0; r < 32; r++) a += sDtl[r][tt] * sW[g][r];
            sDt[g][tt] = softplusf(a);
        }
        __syncthreads();
#pragma unroll
        for (int tt = 0; tt < 64; tt++) {
            float dt = sDt[g][tt];
            float dA = __expf(dt * A_n);
            h  = dA * h + (dt * sU[g][tt]) * sB[n][tt];
            Pa *= dA;
        }
        __syncthreads();
    }
    size_t idx = ((size_t)(c * 4 + b) * 1024 + e) * 16 + n;
    Pbuf[idx] = Pa;
    Sbuf[idx] = h;
}

// ---------------------------------------------------------------------------
// K5b: compose the NCH chunk transforms -> h_in per chunk. 65536 threads.
// ---------------------------------------------------------------------------
__global__ __launch_bounds__(256) void k_scan_mid(const float* __restrict__ P,
                                                  const float* __restrict__ S,
                                                  float* __restrict__ hin) {
    int idx = blockIdx.x * 256 + threadIdx.x;   // (b,e,n) flat, 65536
    float acc = 0.f;
#pragma unroll
    for (int c = 0; c < NCH; c++) {
        hin[c * 65536 + idx] = acc;
        acc = S[c * 65536 + idx] + P[c * 65536 + idx] * acc;
    }
}

// ---------------------------------------------------------------------------
// K5c: scan pass 2 — replay chunk from h_in, compute gated y.
// rev=1: z read and y write index-flipped. accum=1: += into y.
// ---------------------------------------------------------------------------
__global__ __launch_bounds__(256) void k_scan_p2(
    const float* __restrict__ xc,    // u
    const float* __restrict__ xdbl,
    const float* __restrict__ xz,    // z rows E..2E-1
    const float* __restrict__ dtw,
    const float* __restrict__ dtb,
    const float* __restrict__ Alog,
    const float* __restrict__ Dp,
    const float* __restrict__ hin,   // [NCH][4][1024][16]
    float* __restrict__ y,
    int rev, int accum)
{
    const int bx = blockIdx.x;
    const int c  = bx >> 8;
    const int j  = bx & 255;
    const int b  = j >> 6;
    const int e0 = (j & 63) << 4;
    const int tid = threadIdx.x;
    const int g = tid >> 4;
    const int n = tid & 15;
    const int e = e0 + g;

    __shared__ float sW[16][33];
    __shared__ float sDtl[32][68];
    __shared__ float sU[16][68];
    __shared__ float sDt[16][68];
    __shared__ float sB[16][68];
    __shared__ float sC[16][68];
    __shared__ float sZ[16][68];

    for (int i = tid; i < 512; i += 256)
        sW[i >> 5][i & 31] = dtw[(size_t)(e0 + (i >> 5)) * 32 + (i & 31)];

    const float A_n     = -__expf(Alog[(size_t)e * Ns + n]);
    const float Dv      = Dp[e];
    const float dt_bias = dtb[e];
    float h = hin[((size_t)(c * 4 + b) * 1024 + e) * 16 + n];

    const float* up  = xc + ((size_t)b * Ei + e) * Lc;
    const float* zp  = xz + ((size_t)b * 2048 + Ei + e) * Lc;
    const float* xdb = xdbl + (size_t)b * 64 * Lc;

    const int tbeg = c * TCH;
    for (int t0 = tbeg; t0 < tbeg + TCH; t0 += 64) {
        *(float4*)&sU[g][n * 4] = *(const float4*)&up[t0 + n * 4];
        *(float4*)&sB[g][n * 4] = *(const float4*)&xdb[(size_t)(32 + g) * Lc + t0 + n * 4];
        *(float4*)&sC[g][n * 4] = *(const float4*)&xdb[(size_t)(48 + g) * Lc + t0 + n * 4];
#pragma unroll
        for (int jj = 0; jj < 4; jj++) {
            int tt = n * 4 + jj;
            int gi = rev ? (Lc - 1 - (t0 + tt)) : (t0 + tt);
            sZ[g][tt] = zp[gi];
        }
#pragma unroll
        for (int f = 0; f < 2; f++) {
            int fi = tid * 2 + f;
            int row = fi >> 4, c4 = (fi & 15) * 4;
            *(float4*)&sDtl[row][c4] = *(const float4*)&xdb[(size_t)row * Lc + t0 + c4];
        }
        __syncthreads();
#pragma unroll
        for (int jj = 0; jj < 4; jj++) {
            int tt = n * 4 + jj;
            float a = dt_bias;
#pragma unroll
            for (int r = 0; r < 32; r++) a += sDtl[r][tt] * sW[g][r];
            sDt[g][tt] = softplusf(a);
        }
        __syncthreads();

        float yb[4];
#pragma unroll
        for (int tt = 0; tt < 64; tt++) {
            float dt = sDt[g][tt];
            float dA = __expf(dt * A_n);
            h = dA * h + (dt * sU[g][tt]) * sB[n][tt];
            float p = h * sC[n][tt];
            p += __shfl_xor(p, 8);
            p += __shfl_xor(p, 4);
            p += __shfl_xor(p, 2);
            p += __shfl_xor(p, 1);
            if (n == (tt & 15)) yb[tt >> 4] = p;
        }

#pragma unroll
        for (int q = 0; q < 4; q++) {
            int tt = q * 16 + n;
            int t  = t0 + tt;
            float val = (yb[q] + Dv * sU[g][tt]) * siluf(sZ[g][tt]);
            size_t idx = ((size_t)b * Ei + e) * Lc + (size_t)(rev ? (Lc - 1 - t) : t);
            if (accum) y[idx] += val;
            else       y[idx] = val;
        }
        __syncthreads();
    }
}

// ---------------------------------------------------------------------------
// K6: out_proj GEMM: out[b][n][m] = sum_e y[b][e][n] * Wout[m][e]
// Epilogue now float4 along m (coalesced).
// ---------------------------------------------------------------------------
__global__ __launch_bounds__(256) void k_gemm_outproj(
    const float* __restrict__ Wout,  // (512,1024)
    const float* __restrict__ y,     // (4,1024,2048)
    float* __restrict__ out)         // (4,2048,512) pre-norm
{
    const int b  = blockIdx.z;
    const int m0 = blockIdx.x * 128;
    const int n0 = blockIdx.y * 128;
    __shared__ float As[16][132];
    __shared__ float Bs[16][132];
    const int tid = threadIdx.x;
    const int tm = tid >> 4, tn = tid & 15;
    const int lr  = tid >> 2;
    const int lc4 = (tid & 3) * 4;
    const int n4 = (tid & 31) * 4;
    const int kr = tid >> 5;

    float acc[8][8];
#pragma unroll
    for (int i = 0; i < 8; i++)
#pragma unroll
        for (int j = 0; j < 8; j++) acc[i][j] = 0.f;

    const float* yb = y + (size_t)b * Ei * Lc;

    for (int k0 = 0; k0 < Ei; k0 += 16) {
#pragma unroll
        for (int half = 0; half < 2; half++) {
            int m = lr + half * 64;
            float4 v = *(const float4*)&Wout[(size_t)(m0 + m) * Ei + k0 + lc4];
            As[lc4 + 0][m] = v.x; As[lc4 + 1][m] = v.y;
            As[lc4 + 2][m] = v.z; As[lc4 + 3][m] = v.w;
        }
#pragma unroll
        for (int kh = 0; kh < 2; kh++) {
            int k = kr + kh * 8;
            float4 v = *(const float4*)&yb[(size_t)(k0 + k) * Lc + n0 + n4];
            *(float4*)&Bs[k][n4] = v;
        }
        __syncthreads();
#pragma unroll
        for (int kk = 0; kk < 16; kk++) {
            float a[8], bv[8];
            *(float4*)&a[0]  = *(const float4*)&As[kk][tm * 4];
            *(float4*)&a[4]  = *(const float4*)&As[kk][tm * 4 + 64];
            *(float4*)&bv[0] = *(const float4*)&Bs[kk][tn * 4];
            *(float4*)&bv[4] = *(const float4*)&Bs[kk][tn * 4 + 64];
#pragma unroll
            for (int i = 0; i < 8; i++)
#pragma unroll
                for (int j = 0; j < 8; j++) acc[i][j] += a[i] * bv[j];
        }
        __syncthreads();
    }
    float* ob = out + (size_t)b * Lc * Dm;
#pragma unroll
    for (int j = 0; j < 8; j++) {
        int nn = n0 + (j < 4 ? tn * 4 + j : 64 + tn * 4 + (j - 4));
        float4 v0 = make_float4(acc[0][j], acc[1][j], acc[2][j], acc[3][j]);
        float4 v1 = make_float4(acc[4][j], acc[5][j], acc[6][j], acc[7][j]);
        *(float4*)&ob[(size_t)nn * Dm + m0 + tm * 4]      = v0;
        *(float4*)&ob[(size_t)nn * Dm + m0 + 64 + tm * 4] = v1;
    }
}

// ---------------------------------------------------------------------------
// K7: fused residual add + RMSNorm (in place on d_out).
// ---------------------------------------------------------------------------
__global__ __launch_bounds__(256) void k_rms(float* __restrict__ out,
                                             const float* __restrict__ resid,
                                             const float* __restrict__ w) {
    int row  = blockIdx.x * 4 + (threadIdx.x >> 6);
    int lane = threadIdx.x & 63;
    float4* po = (float4*)(out + (size_t)row * Dm);
    const float4* pr = (const float4*)(resid + (size_t)row * Dm);
    const float4* pw = (const float4*)w;
    float4 a0 = po[lane], a1 = po[lane + 64];
    float4 r0 = pr[lane], r1 = pr[lane + 64];
    a0.x += r0.x; a0.y += r0.y; a0.z += r0.z; a0.w += r0.w;
    a1.x += r1.x; a1.y += r1.y; a1.z += r1.z; a1.w += r1.w;
    float q = a0.x * a0.x + a0.y * a0.y + a0.z * a0.z + a0.w * a0.w +
              a1.x * a1.x + a1.y * a1.y + a1.z * a1.z + a1.w * a1.w;
#pragma unroll
    for (int off = 32; off >= 1; off >>= 1) q += __shfl_xor(q, off);
    float scale = rsqrtf(q * (1.f / Dm) + EPSf);
    float4 w0 = pw[lane], w1 = pw[lane + 64];
    a0.x *= scale * w0.x; a0.y *= scale * w0.y; a0.z *= scale * w0.z; a0.w *= scale * w0.w;
    a1.x *= scale * w1.x; a1.y *= scale * w1.y; a1.z *= scale * w1.z; a1.w *= scale * w1.w;
    po[lane] = a0;
    po[lane + 64] = a1;
}

// ---------------------------------------------------------------------------
extern "C" void kernel_launch(void* const* d_in, const int* in_sizes, int n_in,
                              void* d_out, int out_size, void* d_ws, size_t ws_size,
                              hipStream_t stream) {
    const float* inp   = (const float*)d_in[0];
    const float* nw    = (const float*)d_in[1];
    const float* nbv   = (const float*)d_in[2];
    const float* Win   = (const float*)d_in[3];
    const float* cwf   = (const float*)d_in[4];
    const float* cbf   = (const float*)d_in[5];
    const float* xpwf  = (const float*)d_in[6];
    const float* dtwf  = (const float*)d_in[7];
    const float* dtbf  = (const float*)d_in[8];
    const float* Alogf = (const float*)d_in[9];
    const float* Df    = (const float*)d_in[10];
    const float* cwr   = (const float*)d_in[11];
    const float* cbr   = (const float*)d_in[12];
    const float* xpwr  = (const float*)d_in[13];
    const float* dtwr  = (const float*)d_in[14];
    const float* dtbr  = (const float*)d_in[15];
    const float* Alogr = (const float*)d_in[16];
    const float* Dr    = (const float*)d_in[17];
    const float* Wout  = (const float*)d_in[18];
    const float* nfw   = (const float*)d_in[19];
    float* outp = (float*)d_out;
    float* ws   = (float*)d_ws;

    float* stats = ws;                                   // 16K floats
    float* xz    = ws + 16384;                           // 4*2048*2048
    float* xc    = xz + (size_t)4 * 2048 * 2048;         // 4*1024*2048
    float* xdbl  = xc + (size_t)4 * 1024 * 2048;         // 4*64*2048
    float* y     = xdbl + (size_t)4 * 64 * 2048;         // 4*1024*2048

    // P/S/hin scratch lives in d_out (16M floats; overwritten by out_proj at
    // the very end). Each buffer is NCH*4*1024*16 = 524288 floats.
    float* Pb   = outp;
    float* Sb   = outp + 524288;
    float* hinb = outp + 2 * 524288;

    k_ln_stats<<<2048, 256, 0, stream>>>(inp, stats);
    k_gemm_inproj<<<dim3(16, 16, 4), 256, 0, stream>>>(Win, inp, stats, nw, nbv, xz);

    // forward branch
    k_conv<<<(4 * 1024 * 2048) / 256, 256, 0, stream>>>(xz, cwf, cbf, xc, 0);
    k_gemm_xdbl<<<dim3(1, 16, 4), 256, 0, stream>>>(xpwf, xc, xdbl);
    k_scan_p1<<<NCH * 256, 256, 0, stream>>>(xc, xdbl, dtwf, dtbf, Alogf, Pb, Sb);
    k_scan_mid<<<256, 256, 0, stream>>>(Pb, Sb, hinb);
    k_scan_p2<<<NCH * 256, 256, 0, stream>>>(xc, xdbl, xz, dtwf, dtbf, Alogf, Df, hinb, y, 0, 0);

    // reverse branch (index-reversed, accumulates into y)
    k_conv<<<(4 * 1024 * 2048) / 256, 256, 0, stream>>>(xz, cwr, cbr, xc, 1);
    k_gemm_xdbl<<<dim3(1, 16, 4), 256, 0, stream>>>(xpwr, xc, xdbl);
    k_scan_p1<<<NCH * 256, 256, 0, stream>>>(xc, xdbl, dtwr, dtbr, Alogr, Pb, Sb);
    k_scan_mid<<<256, 256, 0, stream>>>(Pb, Sb, hinb);
    k_scan_p2<<<NCH * 256, 256, 0, stream>>>(xc, xdbl, xz, dtwr, dtbr, Alogr, Dr, hinb, y, 1, 1);

    k_gemm_outproj<<<dim3(4, 16, 4), 256, 0, stream>>>(Wout, y, outp);
    k_rms<<<2048, 256, 0, stream>>>(outp, inp, nfw);
}

// Round 3
// 792.360 us; speedup vs baseline: 1.4181x; 1.3299x over previous
//
#include <hip/hip_runtime.h>
#include <math.h>
#include <stdint.h>

// Problem constants
#define Bb 4
#define Lc 2048
#define Dm 512
#define Ei 1024     // E = 2*D_MODEL
#define Ns 16       // d_state
#define Rr 32       // dt_rank
#define EPSf 1e-5f
#define NCH 16      // scan chunks
#define TCH 128     // timesteps per chunk
#define LDS_S 40    // padded LDS row stride (ushorts) for MFMA tiles

typedef __attribute__((ext_vector_type(8))) short bf16x8;
typedef __attribute__((ext_vector_type(4))) float f32x4;

__device__ __forceinline__ float siluf(float x) {
    return x / (1.f + __expf(-x));
}
__device__ __forceinline__ float softplusf(float x) {
    return x > 20.f ? x : log1pf(__expf(x));
}
__device__ __forceinline__ unsigned short f2bf(float x) {
    union { float f; unsigned u; } v; v.f = x;
    unsigned r = (v.u + 0x7FFFu + ((v.u >> 16) & 1u)) >> 16;
    return (unsigned short)r;
}
__device__ __forceinline__ float bf2f(unsigned short x) {
    union { unsigned u; float f; } v; v.u = ((unsigned)x) << 16;
    return v.f;
}

// ---------------------------------------------------------------------------
// K1: LayerNorm -> bf16 h. One wave per row (D=512), 4 rows/block.
// ---------------------------------------------------------------------------
__global__ __launch_bounds__(256) void k_ln(const float* __restrict__ inp,
                                            const float* __restrict__ nw,
                                            const float* __restrict__ nb,
                                            unsigned short* __restrict__ hbf) {
    int row  = blockIdx.x * 4 + (threadIdx.x >> 6);
    int lane = threadIdx.x & 63;
    const float4* p = (const float4*)(inp + (size_t)row * Dm);
    float4 v0 = p[lane];
    float4 v1 = p[lane + 64];
    float s = v0.x + v0.y + v0.z + v0.w + v1.x + v1.y + v1.z + v1.w;
    float q = v0.x * v0.x + v0.y * v0.y + v0.z * v0.z + v0.w * v0.w +
              v1.x * v1.x + v1.y * v1.y + v1.z * v1.z + v1.w * v1.w;
#pragma unroll
    for (int off = 32; off >= 1; off >>= 1) {
        s += __shfl_xor(s, off);
        q += __shfl_xor(q, off);
    }
    float mu = s * (1.f / Dm);
    float rs = rsqrtf(q * (1.f / Dm) - mu * mu + EPSf);
    int d0 = lane * 4, d1 = 256 + lane * 4;
    float4 w0 = *(const float4*)&nw[d0], w1 = *(const float4*)&nw[d1];
    float4 b0 = *(const float4*)&nb[d0], b1 = *(const float4*)&nb[d1];
    ushort4 o0, o1;
    o0.x = f2bf((v0.x - mu) * rs * w0.x + b0.x);
    o0.y = f2bf((v0.y - mu) * rs * w0.y + b0.y);
    o0.z = f2bf((v0.z - mu) * rs * w0.z + b0.z);
    o0.w = f2bf((v0.w - mu) * rs * w0.w + b0.w);
    o1.x = f2bf((v1.x - mu) * rs * w1.x + b1.x);
    o1.y = f2bf((v1.y - mu) * rs * w1.y + b1.y);
    o1.z = f2bf((v1.z - mu) * rs * w1.z + b1.z);
    o1.w = f2bf((v1.w - mu) * rs * w1.w + b1.w);
    *(ushort4*)&hbf[(size_t)row * Dm + d0] = o0;
    *(ushort4*)&hbf[(size_t)row * Dm + d1] = o1;
}

// ---------------------------------------------------------------------------
// K1b: fp32 -> bf16 cast (4 elems/thread).
// ---------------------------------------------------------------------------
__global__ __launch_bounds__(256) void k_cast(const float* __restrict__ in,
                                              unsigned short* __restrict__ out) {
    size_t i = ((size_t)blockIdx.x * 256 + threadIdx.x) * 4;
    float4 v = *(const float4*)&in[i];
    ushort4 o;
    o.x = f2bf(v.x); o.y = f2bf(v.y); o.z = f2bf(v.z); o.w = f2bf(v.w);
    *(ushort4*)&out[i] = o;
}

// ---------------------------------------------------------------------------
// K2: in_proj bf16 MFMA GEMM.  xz[b][m][n] = sum_k W[m][k] * h[b*L+n][k]
// M=2048, N=2048/b, K=512. Tile 128x128, BK=32, 4 waves, 4x4 16x16 frags/wave.
// A-frag lane l: A[l&15][(l>>4)*8+j]; B-frag lane l: h_row[l&15][(l>>4)*8+j];
// D lane l reg r: C[(l>>4)*4+r][l&15]   (m89/m91-verified mapping).
// ---------------------------------------------------------------------------
__global__ __launch_bounds__(256) void k_mfma_inproj(
    const unsigned short* __restrict__ Wbf,  // (2048,512) bf16
    const unsigned short* __restrict__ hbf,  // (8192,512) bf16
    float* __restrict__ xz)                  // (4,2048,2048)
{
    const int b  = blockIdx.z;
    const int m0 = blockIdx.x * 128;
    const int n0 = blockIdx.y * 128;
    __shared__ __align__(16) unsigned short lA[128 * LDS_S];
    __shared__ __align__(16) unsigned short lB[128 * LDS_S];
    const int tid  = threadIdx.x;
    const int lane = tid & 63;
    const int w    = tid >> 6;
    const int wr   = w >> 1, wc = w & 1;

    f32x4 acc[4][4] = {};

    const unsigned short* hb = hbf + ((size_t)b * Lc + n0) * Dm;
    const unsigned short* Wb = Wbf + (size_t)m0 * Dm;

    for (int k0 = 0; k0 < Dm; k0 += 32) {
#pragma unroll
        for (int i = 0; i < 2; i++) {
            int c = tid + i * 256;            // 512 16B-chunks per tile
            int row = c >> 2, col = (c & 3) * 8;
            *(uint4*)&lA[row * LDS_S + col] = *(const uint4*)&Wb[(size_t)row * Dm + k0 + col];
            *(uint4*)&lB[row * LDS_S + col] = *(const uint4*)&hb[(size_t)row * Dm + k0 + col];
        }
        __syncthreads();
        bf16x8 aF[4], bF[4];
#pragma unroll
        for (int f = 0; f < 4; f++) {
            aF[f] = *(bf16x8*)&lA[(wr * 64 + f * 16 + (lane & 15)) * LDS_S + (lane >> 4) * 8];
            bF[f] = *(bf16x8*)&lB[(wc * 64 + f * 16 + (lane & 15)) * LDS_S + (lane >> 4) * 8];
        }
#pragma unroll
        for (int i = 0; i < 4; i++)
#pragma unroll
            for (int j = 0; j < 4; j++)
                acc[i][j] = __builtin_amdgcn_mfma_f32_16x16x32_bf16(aF[i], bF[j], acc[i][j], 0, 0, 0);
        __syncthreads();
    }
    float* Cb = xz + (size_t)b * 2048 * Lc;
#pragma unroll
    for (int i = 0; i < 4; i++) {
        int mbase = m0 + wr * 64 + i * 16 + (lane >> 4) * 4;
#pragma unroll
        for (int j = 0; j < 4; j++) {
            int nn = n0 + wc * 64 + j * 16 + (lane & 15);
#pragma unroll
            for (int r = 0; r < 4; r++)
                Cb[(size_t)(mbase + r) * Lc + nn] = acc[i][j][r];
        }
    }
}

// ---------------------------------------------------------------------------
// K3: causal depthwise conv (K=4) + SiLU.  rev=1 reads time-reversed input.
// ---------------------------------------------------------------------------
__global__ __launch_bounds__(256) void k_conv(const float* __restrict__ xz,
                                              const float* __restrict__ cw,
                                              const float* __restrict__ cb,
                                              float* __restrict__ xc, int rev) {
    size_t idx = (size_t)blockIdx.x * 256 + threadIdx.x;  // < B*E*L
    int l = (int)(idx & (Lc - 1));
    size_t ce = idx >> 11;
    int e = (int)(ce & (Ei - 1));
    int b = (int)(ce >> 10);
    const float* x = xz + ((size_t)b * 2048 + e) * Lc;
    float acc = cb[e];
    float wv[4] = {cw[e * 4], cw[e * 4 + 1], cw[e * 4 + 2], cw[e * 4 + 3]};
#pragma unroll
    for (int i = 0; i < 4; i++) {
        int j = l - 3 + i;
        if (j >= 0) acc += wv[i] * x[rev ? (Lc - 1 - j) : j];
    }
    xc[((size_t)b * Ei + e) * Lc + l] = siluf(acc);
}

// ---------------------------------------------------------------------------
// K4: x_proj GEMM (fp32): xdbl[b][m][n] = sum_e xc[b][e][n] * xpw[m][e]
// ---------------------------------------------------------------------------
__global__ __launch_bounds__(256) void k_gemm_xdbl(
    const float* __restrict__ xpw,  // (64,1024)
    const float* __restrict__ xc,   // (4,1024,2048)
    float* __restrict__ xdbl)       // (4,64,2048)
{
    const int b  = blockIdx.z;
    const int n0 = blockIdx.y * 128;
    __shared__ float As[16][68];
    __shared__ float Bs[16][132];
    const int tid = threadIdx.x;
    const int tm = tid >> 4, tn = tid & 15;
    const int lr  = tid >> 2;
    const int lc4 = (tid & 3) * 4;
    const int n4 = (tid & 31) * 4;
    const int kr = tid >> 5;  // 0..7

    float acc[4][8];
#pragma unroll
    for (int i = 0; i < 4; i++)
#pragma unroll
        for (int j = 0; j < 8; j++) acc[i][j] = 0.f;

    const float* xcb = xc + (size_t)b * Ei * Lc;

    for (int k0 = 0; k0 < Ei; k0 += 16) {
        {
            float4 v = *(const float4*)&xpw[(size_t)lr * Ei + k0 + lc4];
            As[lc4 + 0][lr] = v.x; As[lc4 + 1][lr] = v.y;
            As[lc4 + 2][lr] = v.z; As[lc4 + 3][lr] = v.w;
        }
#pragma unroll
        for (int kh = 0; kh < 2; kh++) {
            int k = kr + kh * 8;
            float4 v = *(const float4*)&xcb[(size_t)(k0 + k) * Lc + n0 + n4];
            *(float4*)&Bs[k][n4] = v;
        }
        __syncthreads();
#pragma unroll
        for (int kk = 0; kk < 16; kk++) {
            float a[4], bv[8];
            *(float4*)&a[0]  = *(const float4*)&As[kk][tm * 4];
            *(float4*)&bv[0] = *(const float4*)&Bs[kk][tn * 4];
            *(float4*)&bv[4] = *(const float4*)&Bs[kk][tn * 4 + 64];
#pragma unroll
            for (int i = 0; i < 4; i++)
#pragma unroll
                for (int j = 0; j < 8; j++) acc[i][j] += a[i] * bv[j];
        }
        __syncthreads();
    }
    float* xd = xdbl + (size_t)b * 64 * Lc;
#pragma unroll
    for (int i = 0; i < 4; i++) {
        int m = tm * 4 + i;
        *(float4*)&xd[(size_t)m * Lc + n0 + tn * 4] =
            make_float4(acc[i][0], acc[i][1], acc[i][2], acc[i][3]);
        *(float4*)&xd[(size_t)m * Lc + n0 + 64 + tn * 4] =
            make_float4(acc[i][4], acc[i][5], acc[i][6], acc[i][7]);
    }
}

// ---------------------------------------------------------------------------
// K5a: scan pass 1 — per-chunk affine transform (P = prod dA, S = local h).
// ---------------------------------------------------------------------------
__global__ __launch_bounds__(256) void k_scan_p1(
    const float* __restrict__ xc,    // u
    const float* __restrict__ xdbl,
    const float* __restrict__ dtw,
    const float* __restrict__ dtb,
    const float* __restrict__ Alog,
    float* __restrict__ Pbuf,        // [NCH][4][1024][16]
    float* __restrict__ Sbuf)
{
    const int bx = blockIdx.x;
    const int c  = bx >> 8;          // chunk
    const int j  = bx & 255;
    const int b  = j >> 6;
    const int e0 = (j & 63) << 4;
    const int tid = threadIdx.x;
    const int g = tid >> 4;          // channel group 0..15
    const int n = tid & 15;          // state index
    const int e = e0 + g;

    __shared__ float sW[16][33];
    __shared__ float sDtl[32][68];
    __shared__ float sU[16][68];
    __shared__ float sDt[16][68];
    __shared__ float sB[16][68];

    for (int i = tid; i < 512; i += 256)
        sW[i >> 5][i & 31] = dtw[(size_t)(e0 + (i >> 5)) * 32 + (i & 31)];

    const float A_n     = -__expf(Alog[(size_t)e * Ns + n]);
    const float dt_bias = dtb[e];
    float h = 0.f, Pa = 1.f;

    const float* up  = xc + ((size_t)b * Ei + e) * Lc;
    const float* xdb = xdbl + (size_t)b * 64 * Lc;

    const int tbeg = c * TCH;
    for (int t0 = tbeg; t0 < tbeg + TCH; t0 += 64) {
        *(float4*)&sU[g][n * 4] = *(const float4*)&up[t0 + n * 4];
        *(float4*)&sB[g][n * 4] = *(const float4*)&xdb[(size_t)(32 + g) * Lc + t0 + n * 4];
#pragma unroll
        for (int f = 0; f < 2; f++) {
            int fi = tid * 2 + f;
            int row = fi >> 4, c4 = (fi & 15) * 4;
            *(float4*)&sDtl[row][c4] = *(const float4*)&xdb[(size_t)row * Lc + t0 + c4];
        }
        __syncthreads();
#pragma unroll
        for (int jj = 0; jj < 4; jj++) {
            int tt = n * 4 + jj;
            float a = dt_bias;
#pragma unroll
            for (int r = 0; r < 32; r++) a += sDtl[r][tt] * sW[g][r];
            sDt[g][tt] = softplusf(a);
        }
        __syncthreads();
#pragma unroll
        for (int tt = 0; tt < 64; tt++) {
            float dt = sDt[g][tt];
            float dA = __expf(dt * A_n);
            h  = dA * h + (dt * sU[g][tt]) * sB[n][tt];
            Pa *= dA;
        }
        __syncthreads();
    }
    size_t idx = ((size_t)(c * 4 + b) * 1024 + e) * 16 + n;
    Pbuf[idx] = Pa;
    Sbuf[idx] = h;
}

// ---------------------------------------------------------------------------
// K5b: compose NCH chunk transforms -> h_in per chunk. 65536 threads.
// ---------------------------------------------------------------------------
__global__ __launch_bounds__(256) void k_scan_mid(const float* __restrict__ P,
                                                  const float* __restrict__ S,
                                                  float* __restrict__ hin) {
    int idx = blockIdx.x * 256 + threadIdx.x;   // (b,e,n) flat, 65536
    float acc = 0.f;
#pragma unroll
    for (int c = 0; c < NCH; c++) {
        hin[c * 65536 + idx] = acc;
        acc = S[c * 65536 + idx] + P[c * 65536 + idx] * acc;
    }
}

// ---------------------------------------------------------------------------
// K5c: scan pass 2 — replay chunk from h_in, gated y -> bf16 ybf[b][t][e].
// rev=0: ybf = val.   rev=1: ybf = bf(val + bf2f(ybf)) at reversed t.
// ---------------------------------------------------------------------------
__global__ __launch_bounds__(256) void k_scan_p2(
    const float* __restrict__ xc,    // u
    const float* __restrict__ xdbl,
    const float* __restrict__ xz,    // z rows E..2E-1
    const float* __restrict__ dtw,
    const float* __restrict__ dtb,
    const float* __restrict__ Alog,
    const float* __restrict__ Dp,
    const float* __restrict__ hin,   // [NCH][4][1024][16]
    unsigned short* __restrict__ ybf,// (4,2048,1024) bf16
    int rev)
{
    const int bx = blockIdx.x;
    const int c  = bx >> 8;
    const int j  = bx & 255;
    const int b  = j >> 6;
    const int e0 = (j & 63) << 4;
    const int tid = threadIdx.x;
    const int g = tid >> 4;
    const int n = tid & 15;
    const int e = e0 + g;

    __shared__ float sW[16][33];
    __shared__ float sDtl[32][68];
    __shared__ float sU[16][68];
    __shared__ float sDt[16][68];
    __shared__ float sB[16][68];
    __shared__ float sC[16][68];
    __shared__ float sZ[16][68];

    for (int i = tid; i < 512; i += 256)
        sW[i >> 5][i & 31] = dtw[(size_t)(e0 + (i >> 5)) * 32 + (i & 31)];

    const float A_n     = -__expf(Alog[(size_t)e * Ns + n]);
    const float Dv      = Dp[e];
    const float dt_bias = dtb[e];
    float h = hin[((size_t)(c * 4 + b) * 1024 + e) * 16 + n];

    const float* up  = xc + ((size_t)b * Ei + e) * Lc;
    const float* zp  = xz + ((size_t)b * 2048 + Ei + e) * Lc;
    const float* xdb = xdbl + (size_t)b * 64 * Lc;

    const int tbeg = c * TCH;
    for (int t0 = tbeg; t0 < tbeg + TCH; t0 += 64) {
        *(float4*)&sU[g][n * 4] = *(const float4*)&up[t0 + n * 4];
        *(float4*)&sB[g][n * 4] = *(const float4*)&xdb[(size_t)(32 + g) * Lc + t0 + n * 4];
        *(float4*)&sC[g][n * 4] = *(const float4*)&xdb[(size_t)(48 + g) * Lc + t0 + n * 4];
#pragma unroll
        for (int jj = 0; jj < 4; jj++) {
            int tt = n * 4 + jj;
            int gi = rev ? (Lc - 1 - (t0 + tt)) : (t0 + tt);
            sZ[g][tt] = zp[gi];
        }
#pragma unroll
        for (int f = 0; f < 2; f++) {
            int fi = tid * 2 + f;
            int row = fi >> 4, c4 = (fi & 15) * 4;
            *(float4*)&sDtl[row][c4] = *(const float4*)&xdb[(size_t)row * Lc + t0 + c4];
        }
        __syncthreads();
#pragma unroll
        for (int jj = 0; jj < 4; jj++) {
            int tt = n * 4 + jj;
            float a = dt_bias;
#pragma unroll
            for (int r = 0; r < 32; r++) a += sDtl[r][tt] * sW[g][r];
            sDt[g][tt] = softplusf(a);
        }
        __syncthreads();

        float yb[4];
#pragma unroll
        for (int tt = 0; tt < 64; tt++) {
            float dt = sDt[g][tt];
            float dA = __expf(dt * A_n);
            h = dA * h + (dt * sU[g][tt]) * sB[n][tt];
            float p = h * sC[n][tt];
            p += __shfl_xor(p, 8);
            p += __shfl_xor(p, 4);
            p += __shfl_xor(p, 2);
            p += __shfl_xor(p, 1);
            if (n == (tt & 15)) yb[tt >> 4] = p;
        }

#pragma unroll
        for (int q = 0; q < 4; q++) {
            int tt = q * 16 + n;
            int t  = t0 + tt;
            float val = (yb[q] + Dv * sU[g][tt]) * siluf(sZ[g][tt]);
            int ti = rev ? (Lc - 1 - t) : t;
            size_t idx = ((size_t)b * Lc + ti) * Ei + e;
            if (rev) val += bf2f(ybf[idx]);
            ybf[idx] = f2bf(val);
        }
        __syncthreads();
    }
}

// ---------------------------------------------------------------------------
// K6: out_proj bf16 MFMA GEMM. out[b][n][m] = sum_e Wout[m][e]*ybf[b][n][e]
// M=512, N=2048/b, K=1024. Tile 64x128, BK=32, 4 waves (2x2), 2x4 frags/wave.
// ---------------------------------------------------------------------------
__global__ __launch_bounds__(256) void k_mfma_outproj(
    const unsigned short* __restrict__ Wbf,  // (512,1024) bf16
    const unsigned short* __restrict__ ybf,  // (4,2048,1024) bf16
    float* __restrict__ out)                 // (4,2048,512)
{
    const int b  = blockIdx.z;
    const int m0 = blockIdx.x * 64;
    const int n0 = blockIdx.y * 128;
    __shared__ __align__(16) unsigned short lA[64 * LDS_S];
    __shared__ __align__(16) unsigned short lB[128 * LDS_S];
    const int tid  = threadIdx.x;
    const int lane = tid & 63;
    const int w    = tid >> 6;
    const int wr   = w >> 1, wc = w & 1;

    f32x4 acc[2][4] = {};

    const unsigned short* yb = ybf + ((size_t)b * Lc + n0) * Ei;
    const unsigned short* Wb = Wbf + (size_t)m0 * Ei;

    for (int k0 = 0; k0 < Ei; k0 += 32) {
        {
            int c = tid;                     // 256 chunks for A (64 rows)
            int row = c >> 2, col = (c & 3) * 8;
            *(uint4*)&lA[row * LDS_S + col] = *(const uint4*)&Wb[(size_t)row * Ei + k0 + col];
        }
#pragma unroll
        for (int i = 0; i < 2; i++) {
            int c = tid + i * 256;           // 512 chunks for B (128 rows)
            int row = c >> 2, col = (c & 3) * 8;
            *(uint4*)&lB[row * LDS_S + col] = *(const uint4*)&yb[(size_t)row * Ei + k0 + col];
        }
        __syncthreads();
        bf16x8 aF[2], bF[4];
#pragma unroll
        for (int f = 0; f < 2; f++)
            aF[f] = *(bf16x8*)&lA[(wr * 32 + f * 16 + (lane & 15)) * LDS_S + (lane >> 4) * 8];
#pragma unroll
        for (int f = 0; f < 4; f++)
            bF[f] = *(bf16x8*)&lB[(wc * 64 + f * 16 + (lane & 15)) * LDS_S + (lane >> 4) * 8];
#pragma unroll
        for (int i = 0; i < 2; i++)
#pragma unroll
            for (int j = 0; j < 4; j++)
                acc[i][j] = __builtin_amdgcn_mfma_f32_16x16x32_bf16(aF[i], bF[j], acc[i][j], 0, 0, 0);
        __syncthreads();
    }
    float* ob = out + (size_t)b * Lc * Dm;
#pragma unroll
    for (int i = 0; i < 2; i++) {
        int mm = m0 + wr * 32 + i * 16 + (lane >> 4) * 4;
#pragma unroll
        for (int j = 0; j < 4; j++) {
            int nn = n0 + wc * 64 + j * 16 + (lane & 15);
            *(f32x4*)&ob[(size_t)nn * Dm + mm] = acc[i][j];
        }
    }
}

// ---------------------------------------------------------------------------
// K7: fused residual add + RMSNorm (in place on d_out).
// ---------------------------------------------------------------------------
__global__ __launch_bounds__(256) void k_rms(float* __restrict__ out,
                                             const float* __restrict__ resid,
                                             const float* __restrict__ w) {
    int row  = blockIdx.x * 4 + (threadIdx.x >> 6);
    int lane = threadIdx.x & 63;
    float4* po = (float4*)(out + (size_t)row * Dm);
    const float4* pr = (const float4*)(resid + (size_t)row * Dm);
    const float4* pw = (const float4*)w;
    float4 a0 = po[lane], a1 = po[lane + 64];
    float4 r0 = pr[lane], r1 = pr[lane + 64];
    a0.x += r0.x; a0.y += r0.y; a0.z += r0.z; a0.w += r0.w;
    a1.x += r1.x; a1.y += r1.y; a1.z += r1.z; a1.w += r1.w;
    float q = a0.x * a0.x + a0.y * a0.y + a0.z * a0.z + a0.w * a0.w +
              a1.x * a1.x + a1.y * a1.y + a1.z * a1.z + a1.w * a1.w;
#pragma unroll
    for (int off = 32; off >= 1; off >>= 1) q += __shfl_xor(q, off);
    float scale = rsqrtf(q * (1.f / Dm) + EPSf);
    float4 w0 = pw[lane], w1 = pw[lane + 64];
    a0.x *= scale * w0.x; a0.y *= scale * w0.y; a0.z *= scale * w0.z; a0.w *= scale * w0.w;
    a1.x *= scale * w1.x; a1.y *= scale * w1.y; a1.z *= scale * w1.z; a1.w *= scale * w1.w;
    po[lane] = a0;
    po[lane + 64] = a1;
}

// ---------------------------------------------------------------------------
extern "C" void kernel_launch(void* const* d_in, const int* in_sizes, int n_in,
                              void* d_out, int out_size, void* d_ws, size_t ws_size,
                              hipStream_t stream) {
    const float* inp   = (const float*)d_in[0];
    const float* nw    = (const float*)d_in[1];
    const float* nbv   = (const float*)d_in[2];
    const float* Win   = (const float*)d_in[3];
    const float* cwf   = (const float*)d_in[4];
    const float* cbf   = (const float*)d_in[5];
    const float* xpwf  = (const float*)d_in[6];
    const float* dtwf  = (const float*)d_in[7];
    const float* dtbf  = (const float*)d_in[8];
    const float* Alogf = (const float*)d_in[9];
    const float* Df    = (const float*)d_in[10];
    const float* cwr   = (const float*)d_in[11];
    const float* cbr   = (const float*)d_in[12];
    const float* xpwr  = (const float*)d_in[13];
    const float* dtwr  = (const float*)d_in[14];
    const float* dtbr  = (const float*)d_in[15];
    const float* Alogr = (const float*)d_in[16];
    const float* Dr    = (const float*)d_in[17];
    const float* Wout  = (const float*)d_in[18];
    const float* nfw   = (const float*)d_in[19];
    float* outp = (float*)d_out;
    float* ws   = (float*)d_ws;

    // workspace layout (floats)
    float* xz   = ws;                                    // 16,777,216
    float* xc   = xz + (size_t)16777216;                 //  8,388,608
    float* xdbl = xc + (size_t)8388608;                  //    524,288
    unsigned short* ybf = (unsigned short*)(xdbl + 524288);  // 8,388,608 bf16
    unsigned short* hbf = ybf + (size_t)8388608;             // 4,194,304 bf16
    unsigned short* wbi = hbf + (size_t)4194304;             // 1,048,576 bf16
    unsigned short* wbo = wbi + (size_t)1048576;             //   524,288 bf16

    // P/S/hin scratch lives in d_out (4.19M floats; overwritten by out_proj
    // at the end). Each buffer NCH*4*1024*16 = 1,048,576 floats.
    float* Pb   = outp;
    float* Sb   = outp + 1048576;
    float* hinb = outp + 2 * 1048576;

    k_ln<<<2048, 256, 0, stream>>>(inp, nw, nbv, hbf);
    k_cast<<<1024, 256, 0, stream>>>(Win, wbi);    // 2048*512
    k_cast<<<512, 256, 0, stream>>>(Wout, wbo);    // 512*1024
    k_mfma_inproj<<<dim3(16, 16, 4), 256, 0, stream>>>(wbi, hbf, xz);

    // forward branch
    k_conv<<<32768, 256, 0, stream>>>(xz, cwf, cbf, xc, 0);
    k_gemm_xdbl<<<dim3(1, 16, 4), 256, 0, stream>>>(xpwf, xc, xdbl);
    k_scan_p1<<<NCH * 256, 256, 0, stream>>>(xc, xdbl, dtwf, dtbf, Alogf, Pb, Sb);
    k_scan_mid<<<256, 256, 0, stream>>>(Pb, Sb, hinb);
    k_scan_p2<<<NCH * 256, 256, 0, stream>>>(xc, xdbl, xz, dtwf, dtbf, Alogf, Df, hinb, ybf, 0);

    // reverse branch (index-reversed, accumulates into ybf)
    k_conv<<<32768, 256, 0, stream>>>(xz, cwr, cbr, xc, 1);
    k_gemm_xdbl<<<dim3(1, 16, 4), 256, 0, stream>>>(xpwr, xc, xdbl);
    k_scan_p1<<<NCH * 256, 256, 0, stream>>>(xc, xdbl, dtwr, dtbr, Alogr, Pb, Sb);
    k_scan_mid<<<256, 256, 0, stream>>>(Pb, Sb, hinb);
    k_scan_p2<<<NCH * 256, 256, 0, stream>>>(xc, xdbl, xz, dtwr, dtbr, Alogr, Dr, hinb, ybf, 1);

    k_mfma_outproj<<<dim3(8, 16, 4), 256, 0, stream>>>(wbo, ybf, outp);
    k_rms<<<2048, 256, 0, stream>>>(outp, inp, nfw);
}

// Round 5
// 582.399 us; speedup vs baseline: 1.9294x; 1.3605x over previous
//
#include <hip/hip_runtime.h>
#include <math.h>
#include <stdint.h>

// Problem constants
#define Bb 4
#define Lc 2048
#define Dm 512
#define Ei 1024     // E = 2*D_MODEL
#define Ns 16       // d_state
#define Rr 32       // dt_rank
#define EPSf 1e-5f
#define NCH 16      // scan chunks
#define TCH 128     // timesteps per chunk
#define LDS_S 40    // padded LDS row stride (ushorts) for MFMA tiles

typedef __attribute__((ext_vector_type(8))) short bf16x8;
typedef __attribute__((ext_vector_type(4))) float f32x4;

__device__ __forceinline__ float siluf(float x) {
    return x / (1.f + __expf(-x));
}
__device__ __forceinline__ float softplusf(float x) {
    return x > 20.f ? x : log1pf(__expf(x));
}
__device__ __forceinline__ unsigned short f2bf(float x) {
    union { float f; unsigned u; } v; v.f = x;
    unsigned r = (v.u + 0x7FFFu + ((v.u >> 16) & 1u)) >> 16;
    return (unsigned short)r;
}
__device__ __forceinline__ float bf2f(unsigned short x) {
    union { unsigned u; float f; } v; v.u = ((unsigned)x) << 16;
    return v.f;
}

// ---------------------------------------------------------------------------
// K1: LayerNorm -> bf16 h. One wave per row (D=512), 4 rows/block.
// ---------------------------------------------------------------------------
__global__ __launch_bounds__(256) void k_ln(const float* __restrict__ inp,
                                            const float* __restrict__ nw,
                                            const float* __restrict__ nb,
                                            unsigned short* __restrict__ hbf) {
    int row  = blockIdx.x * 4 + (threadIdx.x >> 6);
    int lane = threadIdx.x & 63;
    const float4* p = (const float4*)(inp + (size_t)row * Dm);
    float4 v0 = p[lane];
    float4 v1 = p[lane + 64];
    float s = v0.x + v0.y + v0.z + v0.w + v1.x + v1.y + v1.z + v1.w;
    float q = v0.x * v0.x + v0.y * v0.y + v0.z * v0.z + v0.w * v0.w +
              v1.x * v1.x + v1.y * v1.y + v1.z * v1.z + v1.w * v1.w;
#pragma unroll
    for (int off = 32; off >= 1; off >>= 1) {
        s += __shfl_xor(s, off);
        q += __shfl_xor(q, off);
    }
    float mu = s * (1.f / Dm);
    float rs = rsqrtf(q * (1.f / Dm) - mu * mu + EPSf);
    int d0 = lane * 4, d1 = 256 + lane * 4;
    float4 w0 = *(const float4*)&nw[d0], w1 = *(const float4*)&nw[d1];
    float4 b0 = *(const float4*)&nb[d0], b1 = *(const float4*)&nb[d1];
    ushort4 o0, o1;
    o0.x = f2bf((v0.x - mu) * rs * w0.x + b0.x);
    o0.y = f2bf((v0.y - mu) * rs * w0.y + b0.y);
    o0.z = f2bf((v0.z - mu) * rs * w0.z + b0.z);
    o0.w = f2bf((v0.w - mu) * rs * w0.w + b0.w);
    o1.x = f2bf((v1.x - mu) * rs * w1.x + b1.x);
    o1.y = f2bf((v1.y - mu) * rs * w1.y + b1.y);
    o1.z = f2bf((v1.z - mu) * rs * w1.z + b1.z);
    o1.w = f2bf((v1.w - mu) * rs * w1.w + b1.w);
    *(ushort4*)&hbf[(size_t)row * Dm + d0] = o0;
    *(ushort4*)&hbf[(size_t)row * Dm + d1] = o1;
}

// ---------------------------------------------------------------------------
// K1b: fp32 -> bf16 cast (4 elems/thread).
// ---------------------------------------------------------------------------
__global__ __launch_bounds__(256) void k_cast(const float* __restrict__ in,
                                              unsigned short* __restrict__ out) {
    size_t i = ((size_t)blockIdx.x * 256 + threadIdx.x) * 4;
    float4 v = *(const float4*)&in[i];
    ushort4 o;
    o.x = f2bf(v.x); o.y = f2bf(v.y); o.z = f2bf(v.z); o.w = f2bf(v.w);
    *(ushort4*)&out[i] = o;
}

// ---------------------------------------------------------------------------
// K2: in_proj bf16 MFMA GEMM.  xz[b][m][n] = sum_k W[m][k] * h[b*L+n][k]
// ---------------------------------------------------------------------------
__global__ __launch_bounds__(256) void k_mfma_inproj(
    const unsigned short* __restrict__ Wbf,  // (2048,512) bf16
    const unsigned short* __restrict__ hbf,  // (8192,512) bf16
    float* __restrict__ xz)                  // (4,2048,2048)
{
    const int b  = blockIdx.z;
    const int m0 = blockIdx.x * 128;
    const int n0 = blockIdx.y * 128;
    __shared__ __align__(16) unsigned short lA[128 * LDS_S];
    __shared__ __align__(16) unsigned short lB[128 * LDS_S];
    const int tid  = threadIdx.x;
    const int lane = tid & 63;
    const int w    = tid >> 6;
    const int wr   = w >> 1, wc = w & 1;

    f32x4 acc[4][4] = {};

    const unsigned short* hb = hbf + ((size_t)b * Lc + n0) * Dm;
    const unsigned short* Wb = Wbf + (size_t)m0 * Dm;

    for (int k0 = 0; k0 < Dm; k0 += 32) {
#pragma unroll
        for (int i = 0; i < 2; i++) {
            int c = tid + i * 256;            // 512 16B-chunks per tile
            int row = c >> 2, col = (c & 3) * 8;
            *(uint4*)&lA[row * LDS_S + col] = *(const uint4*)&Wb[(size_t)row * Dm + k0 + col];
            *(uint4*)&lB[row * LDS_S + col] = *(const uint4*)&hb[(size_t)row * Dm + k0 + col];
        }
        __syncthreads();
        bf16x8 aF[4], bF[4];
#pragma unroll
        for (int f = 0; f < 4; f++) {
            aF[f] = *(bf16x8*)&lA[(wr * 64 + f * 16 + (lane & 15)) * LDS_S + (lane >> 4) * 8];
            bF[f] = *(bf16x8*)&lB[(wc * 64 + f * 16 + (lane & 15)) * LDS_S + (lane >> 4) * 8];
        }
#pragma unroll
        for (int i = 0; i < 4; i++)
#pragma unroll
            for (int j = 0; j < 4; j++)
                acc[i][j] = __builtin_amdgcn_mfma_f32_16x16x32_bf16(aF[i], bF[j], acc[i][j], 0, 0, 0);
        __syncthreads();
    }
    float* Cb = xz + (size_t)b * 2048 * Lc;
#pragma unroll
    for (int i = 0; i < 4; i++) {
        int mbase = m0 + wr * 64 + i * 16 + (lane >> 4) * 4;
#pragma unroll
        for (int j = 0; j < 4; j++) {
            int nn = n0 + wc * 64 + j * 16 + (lane & 15);
#pragma unroll
            for (int r = 0; r < 4; r++)
                Cb[(size_t)(mbase + r) * Lc + nn] = acc[i][j][r];
        }
    }
}

// ---------------------------------------------------------------------------
// K3: causal depthwise conv (K=4) + SiLU.  rev=1 reads time-reversed input.
// ---------------------------------------------------------------------------
__global__ __launch_bounds__(256) void k_conv(const float* __restrict__ xz,
                                              const float* __restrict__ cw,
                                              const float* __restrict__ cb,
                                              float* __restrict__ xc, int rev) {
    size_t idx = (size_t)blockIdx.x * 256 + threadIdx.x;  // < B*E*L
    int l = (int)(idx & (Lc - 1));
    size_t ce = idx >> 11;
    int e = (int)(ce & (Ei - 1));
    int b = (int)(ce >> 10);
    const float* x = xz + ((size_t)b * 2048 + e) * Lc;
    float acc = cb[e];
    float wv[4] = {cw[e * 4], cw[e * 4 + 1], cw[e * 4 + 2], cw[e * 4 + 3]};
#pragma unroll
    for (int i = 0; i < 4; i++) {
        int j = l - 3 + i;
        if (j >= 0) acc += wv[i] * x[rev ? (Lc - 1 - j) : j];
    }
    xc[((size_t)b * Ei + e) * Lc + l] = siluf(acc);
}

// ---------------------------------------------------------------------------
// K4: x_proj GEMM (fp32): xdbl[b][m][n] = sum_e xc[b][e][n] * xpw[m][e]
// ---------------------------------------------------------------------------
__global__ __launch_bounds__(256) void k_gemm_xdbl(
    const float* __restrict__ xpw,  // (64,1024)
    const float* __restrict__ xc,   // (4,1024,2048)
    float* __restrict__ xdbl)       // (4,64,2048)
{
    const int b  = blockIdx.z;
    const int n0 = blockIdx.y * 128;
    __shared__ float As[16][68];
    __shared__ float Bs[16][132];
    const int tid = threadIdx.x;
    const int tm = tid >> 4, tn = tid & 15;
    const int lr  = tid >> 2;
    const int lc4 = (tid & 3) * 4;
    const int n4 = (tid & 31) * 4;
    const int kr = tid >> 5;  // 0..7

    float acc[4][8];
#pragma unroll
    for (int i = 0; i < 4; i++)
#pragma unroll
        for (int j = 0; j < 8; j++) acc[i][j] = 0.f;

    const float* xcb = xc + (size_t)b * Ei * Lc;

    for (int k0 = 0; k0 < Ei; k0 += 16) {
        {
            float4 v = *(const float4*)&xpw[(size_t)lr * Ei + k0 + lc4];
            As[lc4 + 0][lr] = v.x; As[lc4 + 1][lr] = v.y;
            As[lc4 + 2][lr] = v.z; As[lc4 + 3][lr] = v.w;
        }
#pragma unroll
        for (int kh = 0; kh < 2; kh++) {
            int k = kr + kh * 8;
            float4 v = *(const float4*)&xcb[(size_t)(k0 + k) * Lc + n0 + n4];
            *(float4*)&Bs[k][n4] = v;
        }
        __syncthreads();
#pragma unroll
        for (int kk = 0; kk < 16; kk++) {
            float a[4], bv[8];
            *(float4*)&a[0]  = *(const float4*)&As[kk][tm * 4];
            *(float4*)&bv[0] = *(const float4*)&Bs[kk][tn * 4];
            *(float4*)&bv[4] = *(const float4*)&Bs[kk][tn * 4 + 64];
#pragma unroll
            for (int i = 0; i < 4; i++)
#pragma unroll
                for (int j = 0; j < 8; j++) acc[i][j] += a[i] * bv[j];
        }
        __syncthreads();
    }
    float* xd = xdbl + (size_t)b * 64 * Lc;
#pragma unroll
    for (int i = 0; i < 4; i++) {
        int m = tm * 4 + i;
        *(float4*)&xd[(size_t)m * Lc + n0 + tn * 4] =
            make_float4(acc[i][0], acc[i][1], acc[i][2], acc[i][3]);
        *(float4*)&xd[(size_t)m * Lc + n0 + 64 + tn * 4] =
            make_float4(acc[i][4], acc[i][5], acc[i][6], acc[i][7]);
    }
}

// ---------------------------------------------------------------------------
// K4b: dt = softplus(dtw @ dt_low + bias), computed ONCE per direction.
// Output bf16 [b][e][L]. Block: 16 e x 64 t.  Grid (32, 64, 4).
// ---------------------------------------------------------------------------
__global__ __launch_bounds__(256) void k_dt(
    const float* __restrict__ xdbl,  // (4,64,2048); rows 0..31 = dt_low
    const float* __restrict__ dtw,   // (1024,32)
    const float* __restrict__ dtb,   // (1024)
    unsigned short* __restrict__ dt16) // (4,1024,2048) bf16
{
    const int b  = blockIdx.z;
    const int e0 = blockIdx.y * 16;
    const int t0 = blockIdx.x * 64;
    const int tid = threadIdx.x;
    const int g = tid >> 4;          // local e
    const int n = tid & 15;          // t-quad selector
    const int e = e0 + g;

    __shared__ float sW[16][33];
    __shared__ float sDtl[32][68];

    for (int i = tid; i < 512; i += 256)
        sW[i >> 5][i & 31] = dtw[(size_t)(e0 + (i >> 5)) * 32 + (i & 31)];

    const float* xdb = xdbl + (size_t)b * 64 * Lc;
#pragma unroll
    for (int f = 0; f < 2; f++) {
        int fi = tid * 2 + f;            // 512 float4 slots (32 rows x 16 quads)
        int row = fi >> 4, c4 = (fi & 15) * 4;
        *(float4*)&sDtl[row][c4] = *(const float4*)&xdb[(size_t)row * Lc + t0 + c4];
    }
    __syncthreads();

    const float bias = dtb[e];
    ushort4 oq;
    unsigned short* op = &oq.x;
#pragma unroll
    for (int jj = 0; jj < 4; jj++) {
        int tt = n * 4 + jj;
        float a = bias;
#pragma unroll
        for (int r = 0; r < 32; r++) a += sDtl[r][tt] * sW[g][r];
        op[jj] = f2bf(softplusf(a));
    }
    *(ushort4*)&dt16[((size_t)b * Ei + e) * Lc + t0 + n * 4] = oq;
}

// ---------------------------------------------------------------------------
// K5a: scan pass 1 — per-chunk affine transform (P = prod dA, S = local h).
// ---------------------------------------------------------------------------
__global__ __launch_bounds__(256) void k_scan_p1(
    const float* __restrict__ xc,      // u
    const float* __restrict__ xdbl,
    const unsigned short* __restrict__ dt16,
    const float* __restrict__ Alog,
    float* __restrict__ Pbuf,          // [NCH][4][1024][16]
    float* __restrict__ Sbuf)
{
    const int bx = blockIdx.x;
    const int c  = bx >> 8;
    const int j  = bx & 255;
    const int b  = j >> 6;
    const int e0 = (j & 63) << 4;
    const int tid = threadIdx.x;
    const int g = tid >> 4;
    const int n = tid & 15;
    const int e = e0 + g;

    __shared__ float sDt[16][68];
    __shared__ float sDu[16][68];
    __shared__ float sB[16][68];

    const float A_n = -__expf(Alog[(size_t)e * Ns + n]);
    float h = 0.f, Pa = 1.f;

    const float* up  = xc + ((size_t)b * Ei + e) * Lc;
    const unsigned short* dtp = dt16 + ((size_t)b * Ei + e) * Lc;
    const float* xdb = xdbl + (size_t)b * 64 * Lc;

    const int tbeg = c * TCH;
    for (int t0 = tbeg; t0 < tbeg + TCH; t0 += 64) {
        float4 uq = *(const float4*)&up[t0 + n * 4];
        ushort4 dq = *(const ushort4*)&dtp[t0 + n * 4];
        float4 dtq = make_float4(bf2f(dq.x), bf2f(dq.y), bf2f(dq.z), bf2f(dq.w));
        *(float4*)&sDt[g][n * 4] = dtq;
        *(float4*)&sDu[g][n * 4] =
            make_float4(dtq.x * uq.x, dtq.y * uq.y, dtq.z * uq.z, dtq.w * uq.w);
        *(float4*)&sB[g][n * 4] = *(const float4*)&xdb[(size_t)(32 + g) * Lc + t0 + n * 4];
        __syncthreads();
#pragma unroll
        for (int tt = 0; tt < 64; tt++) {
            float dA = __expf(sDt[g][tt] * A_n);
            h  = fmaf(dA, h, sDu[g][tt] * sB[n][tt]);
            Pa *= dA;
        }
        __syncthreads();
    }
    size_t idx = ((size_t)(c * 4 + b) * 1024 + e) * 16 + n;
    Pbuf[idx] = Pa;
    Sbuf[idx] = h;
}

// ---------------------------------------------------------------------------
// K5b: compose NCH chunk transforms -> h_in per chunk. 65536 threads.
// ---------------------------------------------------------------------------
__global__ __launch_bounds__(256) void k_scan_mid(const float* __restrict__ P,
                                                  const float* __restrict__ S,
                                                  float* __restrict__ hin) {
    int idx = blockIdx.x * 256 + threadIdx.x;   // (b,e,n) flat, 65536
    float acc = 0.f;
#pragma unroll
    for (int c = 0; c < NCH; c++) {
        hin[c * 65536 + idx] = acc;
        acc = S[c * 65536 + idx] + P[c * 65536 + idx] * acc;
    }
}

// ---------------------------------------------------------------------------
// K5c: scan pass 2 — replay chunk from h_in; y via sP-transpose reduce.
// sP padded [16][17][20]: inner stride 20 floats = 80 B (16B-aligned float4
// reads for every n — the [17] version was misaligned for n%4!=0), mid
// stride 17 de-aligns the g-stride from bank 0.
// ---------------------------------------------------------------------------
__global__ __launch_bounds__(256) void k_scan_p2(
    const float* __restrict__ xc,      // u
    const float* __restrict__ xdbl,
    const float* __restrict__ xz,      // z rows E..2E-1
    const unsigned short* __restrict__ dt16,
    const float* __restrict__ Alog,
    const float* __restrict__ Dp,
    const float* __restrict__ hin,     // [NCH][4][1024][16]
    unsigned short* __restrict__ ybf,  // (4,2048,1024) bf16
    int rev)
{
    const int bx = blockIdx.x;
    const int c  = bx >> 8;
    const int j  = bx & 255;
    const int b  = j >> 6;
    const int e0 = (j & 63) << 4;
    const int tid = threadIdx.x;
    const int g = tid >> 4;
    const int n = tid & 15;
    const int e = e0 + g;

    __shared__ float sDt[16][68];
    __shared__ float sDu[16][68];
    __shared__ float sU[16][68];
    __shared__ float sB[16][68];
    __shared__ float sC[16][68];
    __shared__ float sP[16][17][20];

    const float A_n = -__expf(Alog[(size_t)e * Ns + n]);
    const float Dv  = Dp[e];
    float h = hin[((size_t)(c * 4 + b) * 1024 + e) * 16 + n];

    const float* up  = xc + ((size_t)b * Ei + e) * Lc;
    const float* zp  = xz + ((size_t)b * 2048 + Ei + e) * Lc;
    const unsigned short* dtp = dt16 + ((size_t)b * Ei + e) * Lc;
    const float* xdb = xdbl + (size_t)b * 64 * Lc;

    const int tbeg = c * TCH;
    for (int t0 = tbeg; t0 < tbeg + TCH; t0 += 64) {
        float4 uq = *(const float4*)&up[t0 + n * 4];
        *(float4*)&sU[g][n * 4] = uq;
        ushort4 dq = *(const ushort4*)&dtp[t0 + n * 4];
        float4 dtq = make_float4(bf2f(dq.x), bf2f(dq.y), bf2f(dq.z), bf2f(dq.w));
        *(float4*)&sDt[g][n * 4] = dtq;
        *(float4*)&sDu[g][n * 4] =
            make_float4(dtq.x * uq.x, dtq.y * uq.y, dtq.z * uq.z, dtq.w * uq.w);
        *(float4*)&sB[g][n * 4] = *(const float4*)&xdb[(size_t)(32 + g) * Lc + t0 + n * 4];
        *(float4*)&sC[g][n * 4] = *(const float4*)&xdb[(size_t)(48 + g) * Lc + t0 + n * 4];
        __syncthreads();

#pragma unroll
        for (int s = 0; s < 4; s++) {
            // 16 serial steps; p written to LDS (off the critical chain)
#pragma unroll
            for (int t2 = 0; t2 < 16; t2++) {
                int tt = s * 16 + t2;
                float dA = __expf(sDt[g][tt] * A_n);
                h = fmaf(dA, h, sDu[g][tt] * sB[n][tt]);
                sP[g][t2][n] = h * sC[n][tt];
            }
            // same-wave transposed reduce: lane (g,n) sums states for tt = s*16+n
            float4 p0 = *(float4*)&sP[g][n][0];
            float4 p1 = *(float4*)&sP[g][n][4];
            float4 p2 = *(float4*)&sP[g][n][8];
            float4 p3 = *(float4*)&sP[g][n][12];
            float acc = ((p0.x + p0.y) + (p0.z + p0.w)) + ((p1.x + p1.y) + (p1.z + p1.w)) +
                        ((p2.x + p2.y) + (p2.z + p2.w)) + ((p3.x + p3.y) + (p3.z + p3.w));
            int tt = s * 16 + n;
            int t  = t0 + tt;
            int gi = rev ? (Lc - 1 - t) : t;
            float val = (acc + Dv * sU[g][tt]) * siluf(zp[gi]);
            size_t idx = ((size_t)b * Lc + gi) * Ei + e;
            if (rev) val += bf2f(ybf[idx]);
            ybf[idx] = f2bf(val);
        }
        __syncthreads();
    }
}

// ---------------------------------------------------------------------------
// K6: out_proj bf16 MFMA GEMM. out[b][n][m] = sum_e Wout[m][e]*ybf[b][n][e]
// ---------------------------------------------------------------------------
__global__ __launch_bounds__(256) void k_mfma_outproj(
    const unsigned short* __restrict__ Wbf,  // (512,1024) bf16
    const unsigned short* __restrict__ ybf,  // (4,2048,1024) bf16
    float* __restrict__ out)                 // (4,2048,512)
{
    const int b  = blockIdx.z;
    const int m0 = blockIdx.x * 64;
    const int n0 = blockIdx.y * 128;
    __shared__ __align__(16) unsigned short lA[64 * LDS_S];
    __shared__ __align__(16) unsigned short lB[128 * LDS_S];
    const int tid  = threadIdx.x;
    const int lane = tid & 63;
    const int w    = tid >> 6;
    const int wr   = w >> 1, wc = w & 1;

    f32x4 acc[2][4] = {};

    const unsigned short* yb = ybf + ((size_t)b * Lc + n0) * Ei;
    const unsigned short* Wb = Wbf + (size_t)m0 * Ei;

    for (int k0 = 0; k0 < Ei; k0 += 32) {
        {
            int c = tid;
            int row = c >> 2, col = (c & 3) * 8;
            *(uint4*)&lA[row * LDS_S + col] = *(const uint4*)&Wb[(size_t)row * Ei + k0 + col];
        }
#pragma unroll
        for (int i = 0; i < 2; i++) {
            int c = tid + i * 256;
            int row = c >> 2, col = (c & 3) * 8;
            *(uint4*)&lB[row * LDS_S + col] = *(const uint4*)&yb[(size_t)row * Ei + k0 + col];
        }
        __syncthreads();
        bf16x8 aF[2], bF[4];
#pragma unroll
        for (int f = 0; f < 2; f++)
            aF[f] = *(bf16x8*)&lA[(wr * 32 + f * 16 + (lane & 15)) * LDS_S + (lane >> 4) * 8];
#pragma unroll
        for (int f = 0; f < 4; f++)
            bF[f] = *(bf16x8*)&lB[(wc * 64 + f * 16 + (lane & 15)) * LDS_S + (lane >> 4) * 8];
#pragma unroll
        for (int i = 0; i < 2; i++)
#pragma unroll
            for (int j = 0; j < 4; j++)
                acc[i][j] = __builtin_amdgcn_mfma_f32_16x16x32_bf16(aF[i], bF[j], acc[i][j], 0, 0, 0);
        __syncthreads();
    }
    float* ob = out + (size_t)b * Lc * Dm;
#pragma unroll
    for (int i = 0; i < 2; i++) {
        int mm = m0 + wr * 32 + i * 16 + (lane >> 4) * 4;
#pragma unroll
        for (int j = 0; j < 4; j++) {
            int nn = n0 + wc * 64 + j * 16 + (lane & 15);
            *(f32x4*)&ob[(size_t)nn * Dm + mm] = acc[i][j];
        }
    }
}

// ---------------------------------------------------------------------------
// K7: fused residual add + RMSNorm (in place on d_out).
// ---------------------------------------------------------------------------
__global__ __launch_bounds__(256) void k_rms(float* __restrict__ out,
                                             const float* __restrict__ resid,
                                             const float* __restrict__ w) {
    int row  = blockIdx.x * 4 + (threadIdx.x >> 6);
    int lane = threadIdx.x & 63;
    float4* po = (float4*)(out + (size_t)row * Dm);
    const float4* pr = (const float4*)(resid + (size_t)row * Dm);
    const float4* pw = (const float4*)w;
    float4 a0 = po[lane], a1 = po[lane + 64];
    float4 r0 = pr[lane], r1 = pr[lane + 64];
    a0.x += r0.x; a0.y += r0.y; a0.z += r0.z; a0.w += r0.w;
    a1.x += r1.x; a1.y += r1.y; a1.z += r1.z; a1.w += r1.w;
    float q = a0.x * a0.x + a0.y * a0.y + a0.z * a0.z + a0.w * a0.w +
              a1.x * a1.x + a1.y * a1.y + a1.z * a1.z + a1.w * a1.w;
#pragma unroll
    for (int off = 32; off >= 1; off >>= 1) q += __shfl_xor(q, off);
    float scale = rsqrtf(q * (1.f / Dm) + EPSf);
    float4 w0 = pw[lane], w1 = pw[lane + 64];
    a0.x *= scale * w0.x; a0.y *= scale * w0.y; a0.z *= scale * w0.z; a0.w *= scale * w0.w;
    a1.x *= scale * w1.x; a1.y *= scale * w1.y; a1.z *= scale * w1.z; a1.w *= scale * w1.w;
    po[lane] = a0;
    po[lane + 64] = a1;
}

// ---------------------------------------------------------------------------
extern "C" void kernel_launch(void* const* d_in, const int* in_sizes, int n_in,
                              void* d_out, int out_size, void* d_ws, size_t ws_size,
                              hipStream_t stream) {
    const float* inp   = (const float*)d_in[0];
    const float* nw    = (const float*)d_in[1];
    const float* nbv   = (const float*)d_in[2];
    const float* Win   = (const float*)d_in[3];
    const float* cwf   = (const float*)d_in[4];
    const float* cbf   = (const float*)d_in[5];
    const float* xpwf  = (const float*)d_in[6];
    const float* dtwf  = (const float*)d_in[7];
    const float* dtbf  = (const float*)d_in[8];
    const float* Alogf = (const float*)d_in[9];
    const float* Df    = (const float*)d_in[10];
    const float* cwr   = (const float*)d_in[11];
    const float* cbr   = (const float*)d_in[12];
    const float* xpwr  = (const float*)d_in[13];
    const float* dtwr  = (const float*)d_in[14];
    const float* dtbr  = (const float*)d_in[15];
    const float* Alogr = (const float*)d_in[16];
    const float* Dr    = (const float*)d_in[17];
    const float* Wout  = (const float*)d_in[18];
    const float* nfw   = (const float*)d_in[19];
    float* outp = (float*)d_out;
    float* ws   = (float*)d_ws;

    // workspace layout (floats)
    float* xz   = ws;                                    // 16,777,216
    float* xc   = xz + (size_t)16777216;                 //  8,388,608
    float* xdbl = xc + (size_t)8388608;                  //    524,288
    unsigned short* ybf = (unsigned short*)(xdbl + 524288);  // 8,388,608 bf16
    unsigned short* hbf = ybf + (size_t)8388608;             // 4,194,304 bf16
    unsigned short* wbi = hbf + (size_t)4194304;             // 1,048,576 bf16
    unsigned short* wbo = wbi + (size_t)1048576;             //   524,288 bf16
    unsigned short* dt16 = wbo + (size_t)524288;             // 8,388,608 bf16

    // P/S/hin scratch lives in d_out (4.19M floats; overwritten by out_proj
    // at the end). Each buffer NCH*4*1024*16 = 1,048,576 floats.
    float* Pb   = outp;
    float* Sb   = outp + 1048576;
    float* hinb = outp + 2 * 1048576;

    k_ln<<<2048, 256, 0, stream>>>(inp, nw, nbv, hbf);
    k_cast<<<1024, 256, 0, stream>>>(Win, wbi);    // 2048*512
    k_cast<<<512, 256, 0, stream>>>(Wout, wbo);    // 512*1024
    k_mfma_inproj<<<dim3(16, 16, 4), 256, 0, stream>>>(wbi, hbf, xz);

    // forward branch
    k_conv<<<32768, 256, 0, stream>>>(xz, cwf, cbf, xc, 0);
    k_gemm_xdbl<<<dim3(1, 16, 4), 256, 0, stream>>>(xpwf, xc, xdbl);
    k_dt<<<dim3(32, 64, 4), 256, 0, stream>>>(xdbl, dtwf, dtbf, dt16);
    k_scan_p1<<<NCH * 256, 256, 0, stream>>>(xc, xdbl, dt16, Alogf, Pb, Sb);
    k_scan_mid<<<256, 256, 0, stream>>>(Pb, Sb, hinb);
    k_scan_p2<<<NCH * 256, 256, 0, stream>>>(xc, xdbl, xz, dt16, Alogf, Df, hinb, ybf, 0);

    // reverse branch (index-reversed, accumulates into ybf)
    k_conv<<<32768, 256, 0, stream>>>(xz, cwr, cbr, xc, 1);
    k_gemm_xdbl<<<dim3(1, 16, 4), 256, 0, stream>>>(xpwr, xc, xdbl);
    k_dt<<<dim3(32, 64, 4), 256, 0, stream>>>(xdbl, dtwr, dtbr, dt16);
    k_scan_p1<<<NCH * 256, 256, 0, stream>>>(xc, xdbl, dt16, Alogr, Pb, Sb);
    k_scan_mid<<<256, 256, 0, stream>>>(Pb, Sb, hinb);
    k_scan_p2<<<NCH * 256, 256, 0, stream>>>(xc, xdbl, xz, dt16, Alogr, Dr, hinb, ybf, 1);

    k_mfma_outproj<<<dim3(8, 16, 4), 256, 0, stream>>>(wbo, ybf, outp);
    k_rms<<<2048, 256, 0, stream>>>(outp, inp, nfw);
}

// Round 6
// 418.487 us; speedup vs baseline: 2.6851x; 1.3917x over previous
//
#include <hip/hip_runtime.h>
#include <math.h>
#include <stdint.h>

// Problem constants
#define Bb 4
#define Lc 2048
#define Dm 512
#define Ei 1024     // E = 2*D_MODEL
#define Ns 16       // d_state
#define Rr 32       // dt_rank
#define EPSf 1e-5f
#define NCH 16      // scan chunks
#define TCH 128     // timesteps per chunk
#define LDS_S 40    // padded LDS row stride (ushorts) for MFMA tiles

typedef __attribute__((ext_vector_type(8))) short bf16x8;
typedef __attribute__((ext_vector_type(4))) float f32x4;

__device__ __forceinline__ float siluf(float x) {
    return x / (1.f + __expf(-x));
}
__device__ __forceinline__ float softplusf(float x) {
    return x > 20.f ? x : log1pf(__expf(x));
}
__device__ __forceinline__ unsigned short f2bf(float x) {
    union { float f; unsigned u; } v; v.f = x;
    unsigned r = (v.u + 0x7FFFu + ((v.u >> 16) & 1u)) >> 16;
    return (unsigned short)r;
}
__device__ __forceinline__ float bf2f(unsigned short x) {
    union { unsigned u; float f; } v; v.u = ((unsigned)x) << 16;
    return v.f;
}

// ---------------------------------------------------------------------------
// K1: LayerNorm -> bf16 h. One wave per row (D=512), 4 rows/block.
// ---------------------------------------------------------------------------
__global__ __launch_bounds__(256) void k_ln(const float* __restrict__ inp,
                                            const float* __restrict__ nw,
                                            const float* __restrict__ nb,
                                            unsigned short* __restrict__ hbf) {
    int row  = blockIdx.x * 4 + (threadIdx.x >> 6);
    int lane = threadIdx.x & 63;
    const float4* p = (const float4*)(inp + (size_t)row * Dm);
    float4 v0 = p[lane];
    float4 v1 = p[lane + 64];
    float s = v0.x + v0.y + v0.z + v0.w + v1.x + v1.y + v1.z + v1.w;
    float q = v0.x * v0.x + v0.y * v0.y + v0.z * v0.z + v0.w * v0.w +
              v1.x * v1.x + v1.y * v1.y + v1.z * v1.z + v1.w * v1.w;
#pragma unroll
    for (int off = 32; off >= 1; off >>= 1) {
        s += __shfl_xor(s, off);
        q += __shfl_xor(q, off);
    }
    float mu = s * (1.f / Dm);
    float rs = rsqrtf(q * (1.f / Dm) - mu * mu + EPSf);
    int d0 = lane * 4, d1 = 256 + lane * 4;
    float4 w0 = *(const float4*)&nw[d0], w1 = *(const float4*)&nw[d1];
    float4 b0 = *(const float4*)&nb[d0], b1 = *(const float4*)&nb[d1];
    ushort4 o0, o1;
    o0.x = f2bf((v0.x - mu) * rs * w0.x + b0.x);
    o0.y = f2bf((v0.y - mu) * rs * w0.y + b0.y);
    o0.z = f2bf((v0.z - mu) * rs * w0.z + b0.z);
    o0.w = f2bf((v0.w - mu) * rs * w0.w + b0.w);
    o1.x = f2bf((v1.x - mu) * rs * w1.x + b1.x);
    o1.y = f2bf((v1.y - mu) * rs * w1.y + b1.y);
    o1.z = f2bf((v1.z - mu) * rs * w1.z + b1.z);
    o1.w = f2bf((v1.w - mu) * rs * w1.w + b1.w);
    *(ushort4*)&hbf[(size_t)row * Dm + d0] = o0;
    *(ushort4*)&hbf[(size_t)row * Dm + d1] = o1;
}

// ---------------------------------------------------------------------------
// K1b: fp32 -> bf16 cast (4 elems/thread).
// ---------------------------------------------------------------------------
__global__ __launch_bounds__(256) void k_cast(const float* __restrict__ in,
                                              unsigned short* __restrict__ out) {
    size_t i = ((size_t)blockIdx.x * 256 + threadIdx.x) * 4;
    float4 v = *(const float4*)&in[i];
    ushort4 o;
    o.x = f2bf(v.x); o.y = f2bf(v.y); o.z = f2bf(v.z); o.w = f2bf(v.w);
    *(ushort4*)&out[i] = o;
}

// ---------------------------------------------------------------------------
// K2: in_proj bf16 MFMA GEMM.  xz[b][m][n] = sum_k W[m][k] * h[b*L+n][k]
// ---------------------------------------------------------------------------
__global__ __launch_bounds__(256) void k_mfma_inproj(
    const unsigned short* __restrict__ Wbf,  // (2048,512) bf16
    const unsigned short* __restrict__ hbf,  // (8192,512) bf16
    float* __restrict__ xz)                  // (4,2048,2048)
{
    const int b  = blockIdx.z;
    const int m0 = blockIdx.x * 128;
    const int n0 = blockIdx.y * 128;
    __shared__ __align__(16) unsigned short lA[128 * LDS_S];
    __shared__ __align__(16) unsigned short lB[128 * LDS_S];
    const int tid  = threadIdx.x;
    const int lane = tid & 63;
    const int w    = tid >> 6;
    const int wr   = w >> 1, wc = w & 1;

    f32x4 acc[4][4] = {};

    const unsigned short* hb = hbf + ((size_t)b * Lc + n0) * Dm;
    const unsigned short* Wb = Wbf + (size_t)m0 * Dm;

    for (int k0 = 0; k0 < Dm; k0 += 32) {
#pragma unroll
        for (int i = 0; i < 2; i++) {
            int c = tid + i * 256;            // 512 16B-chunks per tile
            int row = c >> 2, col = (c & 3) * 8;
            *(uint4*)&lA[row * LDS_S + col] = *(const uint4*)&Wb[(size_t)row * Dm + k0 + col];
            *(uint4*)&lB[row * LDS_S + col] = *(const uint4*)&hb[(size_t)row * Dm + k0 + col];
        }
        __syncthreads();
        bf16x8 aF[4], bF[4];
#pragma unroll
        for (int f = 0; f < 4; f++) {
            aF[f] = *(bf16x8*)&lA[(wr * 64 + f * 16 + (lane & 15)) * LDS_S + (lane >> 4) * 8];
            bF[f] = *(bf16x8*)&lB[(wc * 64 + f * 16 + (lane & 15)) * LDS_S + (lane >> 4) * 8];
        }
#pragma unroll
        for (int i = 0; i < 4; i++)
#pragma unroll
            for (int j = 0; j < 4; j++)
                acc[i][j] = __builtin_amdgcn_mfma_f32_16x16x32_bf16(aF[i], bF[j], acc[i][j], 0, 0, 0);
        __syncthreads();
    }
    float* Cb = xz + (size_t)b * 2048 * Lc;
#pragma unroll
    for (int i = 0; i < 4; i++) {
        int mbase = m0 + wr * 64 + i * 16 + (lane >> 4) * 4;
#pragma unroll
        for (int j = 0; j < 4; j++) {
            int nn = n0 + wc * 64 + j * 16 + (lane & 15);
#pragma unroll
            for (int r = 0; r < 4; r++)
                Cb[(size_t)(mbase + r) * Lc + nn] = acc[i][j][r];
        }
    }
}

// ---------------------------------------------------------------------------
// K3: tiled causal depthwise conv (K=4) + SiLU.  Emits bf16 in BOTH layouts:
//   xcE [b][e][L]  (scan u staging)
//   xcT [b][L][e]  (x_proj MFMA B operand, via LDS transpose tile)
// Block: 16 e x 64 l.  Grid (L/64, E/16, B).
// ---------------------------------------------------------------------------
__global__ __launch_bounds__(256) void k_conv(const float* __restrict__ xz,
                                              const float* __restrict__ cw,
                                              const float* __restrict__ cb,
                                              unsigned short* __restrict__ xcE,
                                              unsigned short* __restrict__ xcT,
                                              int rev) {
    const int b  = blockIdx.z;
    const int e0 = blockIdx.y * 16;
    const int t0 = blockIdx.x * 64;
    const int tid = threadIdx.x;
    const int g = tid >> 4;
    const int n = tid & 15;
    const int e = e0 + g;
    const int j0 = t0 + n * 4;

    __shared__ unsigned short sY[64][20];   // stride 40 B: ushort4-aligned rows

    const float* x = xz + ((size_t)b * 2048 + e) * Lc;
    float w0 = cw[e * 4], w1 = cw[e * 4 + 1], w2 = cw[e * 4 + 2], w3 = cw[e * 4 + 3];
    float bias = cb[e];

    float v[8];  // xin[j0-4 .. j0+3] (xin = x or reversed x)
    if (!rev) {
        float4 cur = *(const float4*)&x[j0];
        v[4] = cur.x; v[5] = cur.y; v[6] = cur.z; v[7] = cur.w;
        if (j0 >= 4) {
            float4 prv = *(const float4*)&x[j0 - 4];
            v[0] = prv.x; v[1] = prv.y; v[2] = prv.z; v[3] = prv.w;
        } else { v[0] = v[1] = v[2] = v[3] = 0.f; }
    } else {
        float4 c4 = *(const float4*)&x[Lc - 4 - j0];   // x[Lc-4-j0 .. Lc-1-j0]
        v[4] = c4.w; v[5] = c4.z; v[6] = c4.y; v[7] = c4.x;
        if (j0 >= 4) {
            float4 p4 = *(const float4*)&x[Lc - j0];   // xin[j0-1..j0-4] fwd order
            v[0] = p4.w; v[1] = p4.z; v[2] = p4.y; v[3] = p4.x;
        } else { v[0] = v[1] = v[2] = v[3] = 0.f; }
    }

    ushort4 oq;
    unsigned short* op = &oq.x;
#pragma unroll
    for (int jj = 0; jj < 4; jj++) {
        float a = bias + w0 * v[jj + 1] + w1 * v[jj + 2] + w2 * v[jj + 3] + w3 * v[jj + 4];
        unsigned short s16 = f2bf(siluf(a));
        op[jj] = s16;
        sY[n * 4 + jj][g] = s16;
    }
    *(ushort4*)&xcE[((size_t)b * Ei + e) * Lc + j0] = oq;
    __syncthreads();

    // transpose-tile write: [l][e] rows of 16 e (32 B per row)
    int row = tid >> 2;
    int c4  = (tid & 3) * 4;
    ushort4 tv = *(ushort4*)&sY[row][c4];
    *(ushort4*)&xcT[((size_t)b * Lc + t0 + row) * Ei + e0 + c4] = tv;
}

// ---------------------------------------------------------------------------
// K4: x_proj bf16 MFMA GEMM: xdbl[b][m][n] = sum_e xpw[m][e] * xcT[b][n][e]
// M=64, N=2048/b, K=1024.  4 waves, each owns an n-quadrant (32 n), all m.
// ---------------------------------------------------------------------------
__global__ __launch_bounds__(256) void k_mfma_xdbl(
    const unsigned short* __restrict__ xpb,  // (64,1024) bf16
    const unsigned short* __restrict__ xcT,  // (4,2048,1024) bf16
    float* __restrict__ xdbl)                // (4,64,2048)
{
    const int n0 = blockIdx.x * 128;
    const int b  = blockIdx.y;
    __shared__ __align__(16) unsigned short lA[64 * LDS_S];
    __shared__ __align__(16) unsigned short lB[128 * LDS_S];
    const int tid  = threadIdx.x;
    const int lane = tid & 63;
    const int w    = tid >> 6;

    f32x4 acc[4][2] = {};

    const unsigned short* yb = xcT + ((size_t)b * Lc + n0) * Ei;

    for (int k0 = 0; k0 < Ei; k0 += 32) {
        {
            int c = tid;                     // A: 64 rows x 4 chunks
            int row = c >> 2, col = (c & 3) * 8;
            *(uint4*)&lA[row * LDS_S + col] = *(const uint4*)&xpb[(size_t)row * Ei + k0 + col];
        }
#pragma unroll
        for (int i = 0; i < 2; i++) {
            int c = tid + i * 256;           // B: 128 rows x 4 chunks
            int row = c >> 2, col = (c & 3) * 8;
            *(uint4*)&lB[row * LDS_S + col] = *(const uint4*)&yb[(size_t)row * Ei + k0 + col];
        }
        __syncthreads();
        bf16x8 aF[4], bF[2];
#pragma unroll
        for (int f = 0; f < 4; f++)
            aF[f] = *(bf16x8*)&lA[(f * 16 + (lane & 15)) * LDS_S + (lane >> 4) * 8];
#pragma unroll
        for (int f = 0; f < 2; f++)
            bF[f] = *(bf16x8*)&lB[(w * 32 + f * 16 + (lane & 15)) * LDS_S + (lane >> 4) * 8];
#pragma unroll
        for (int i = 0; i < 4; i++)
#pragma unroll
            for (int j = 0; j < 2; j++)
                acc[i][j] = __builtin_amdgcn_mfma_f32_16x16x32_bf16(aF[i], bF[j], acc[i][j], 0, 0, 0);
        __syncthreads();
    }
    float* xd = xdbl + (size_t)b * 64 * Lc;
#pragma unroll
    for (int i = 0; i < 4; i++) {
        int mbase = i * 16 + (lane >> 4) * 4;
#pragma unroll
        for (int j = 0; j < 2; j++) {
            int nn = n0 + w * 32 + j * 16 + (lane & 15);
#pragma unroll
            for (int r = 0; r < 4; r++)
                xd[(size_t)(mbase + r) * Lc + nn] = acc[i][j][r];
        }
    }
}

// ---------------------------------------------------------------------------
// K4b: dt = softplus(dtw @ dt_low + bias), computed ONCE per direction.
// Output bf16 [b][e][L]. Block: 16 e x 64 t.  Grid (32, 64, 4).
// ---------------------------------------------------------------------------
__global__ __launch_bounds__(256) void k_dt(
    const float* __restrict__ xdbl,  // (4,64,2048); rows 0..31 = dt_low
    const float* __restrict__ dtw,   // (1024,32)
    const float* __restrict__ dtb,   // (1024)
    unsigned short* __restrict__ dt16) // (4,1024,2048) bf16
{
    const int b  = blockIdx.z;
    const int e0 = blockIdx.y * 16;
    const int t0 = blockIdx.x * 64;
    const int tid = threadIdx.x;
    const int g = tid >> 4;          // local e
    const int n = tid & 15;          // t-quad selector
    const int e = e0 + g;

    __shared__ float sW[16][33];
    __shared__ float sDtl[32][68];

    for (int i = tid; i < 512; i += 256)
        sW[i >> 5][i & 31] = dtw[(size_t)(e0 + (i >> 5)) * 32 + (i & 31)];

    const float* xdb = xdbl + (size_t)b * 64 * Lc;
#pragma unroll
    for (int f = 0; f < 2; f++) {
        int fi = tid * 2 + f;            // 512 float4 slots (32 rows x 16 quads)
        int row = fi >> 4, c4 = (fi & 15) * 4;
        *(float4*)&sDtl[row][c4] = *(const float4*)&xdb[(size_t)row * Lc + t0 + c4];
    }
    __syncthreads();

    const float bias = dtb[e];
    ushort4 oq;
    unsigned short* op = &oq.x;
#pragma unroll
    for (int jj = 0; jj < 4; jj++) {
        int tt = n * 4 + jj;
        float a = bias;
#pragma unroll
        for (int r = 0; r < 32; r++) a += sDtl[r][tt] * sW[g][r];
        op[jj] = f2bf(softplusf(a));
    }
    *(ushort4*)&dt16[((size_t)b * Ei + e) * Lc + t0 + n * 4] = oq;
}

// ---------------------------------------------------------------------------
// K5a: scan pass 1 — per-chunk affine transform (P = prod dA, S = local h).
// ---------------------------------------------------------------------------
__global__ __launch_bounds__(256) void k_scan_p1(
    const unsigned short* __restrict__ xcE,   // u (bf16)
    const float* __restrict__ xdbl,
    const unsigned short* __restrict__ dt16,
    const float* __restrict__ Alog,
    float* __restrict__ Pbuf,          // [NCH][4][1024][16]
    float* __restrict__ Sbuf)
{
    const int bx = blockIdx.x;
    const int c  = bx >> 8;
    const int j  = bx & 255;
    const int b  = j >> 6;
    const int e0 = (j & 63) << 4;
    const int tid = threadIdx.x;
    const int g = tid >> 4;
    const int n = tid & 15;
    const int e = e0 + g;

    __shared__ float sDt[16][68];
    __shared__ float sDu[16][68];
    __shared__ float sB[16][68];

    const float A_n = -__expf(Alog[(size_t)e * Ns + n]);
    float h = 0.f, Pa = 1.f;

    const unsigned short* up  = xcE + ((size_t)b * Ei + e) * Lc;
    const unsigned short* dtp = dt16 + ((size_t)b * Ei + e) * Lc;
    const float* xdb = xdbl + (size_t)b * 64 * Lc;

    const int tbeg = c * TCH;
    for (int t0 = tbeg; t0 < tbeg + TCH; t0 += 64) {
        ushort4 uq = *(const ushort4*)&up[t0 + n * 4];
        ushort4 dq = *(const ushort4*)&dtp[t0 + n * 4];
        float4 dtq = make_float4(bf2f(dq.x), bf2f(dq.y), bf2f(dq.z), bf2f(dq.w));
        *(float4*)&sDt[g][n * 4] = dtq;
        *(float4*)&sDu[g][n * 4] =
            make_float4(dtq.x * bf2f(uq.x), dtq.y * bf2f(uq.y),
                        dtq.z * bf2f(uq.z), dtq.w * bf2f(uq.w));
        *(float4*)&sB[g][n * 4] = *(const float4*)&xdb[(size_t)(32 + g) * Lc + t0 + n * 4];
        __syncthreads();
#pragma unroll
        for (int tt = 0; tt < 64; tt++) {
            float dA = __expf(sDt[g][tt] * A_n);
            h  = fmaf(dA, h, sDu[g][tt] * sB[n][tt]);
            Pa *= dA;
        }
        __syncthreads();
    }
    size_t idx = ((size_t)(c * 4 + b) * 1024 + e) * 16 + n;
    Pbuf[idx] = Pa;
    Sbuf[idx] = h;
}

// ---------------------------------------------------------------------------
// K5b: compose NCH chunk transforms -> h_in per chunk. 65536 threads.
// ---------------------------------------------------------------------------
__global__ __launch_bounds__(256) void k_scan_mid(const float* __restrict__ P,
                                                  const float* __restrict__ S,
                                                  float* __restrict__ hin) {
    int idx = blockIdx.x * 256 + threadIdx.x;   // (b,e,n) flat, 65536
    float acc = 0.f;
#pragma unroll
    for (int c = 0; c < NCH; c++) {
        hin[c * 65536 + idx] = acc;
        acc = S[c * 65536 + idx] + P[c * 65536 + idx] * acc;
    }
}

// ---------------------------------------------------------------------------
// K5c: scan pass 2 — replay chunk from h_in; y via sP-transpose reduce;
// gated output staged in LDS tile sY[64][20] then written COALESCED
// (32B rows) to ybf[b][t][e]; rev accumulates via read-modify-write.
// ---------------------------------------------------------------------------
__global__ __launch_bounds__(256) void k_scan_p2(
    const unsigned short* __restrict__ xcE,   // u (bf16)
    const float* __restrict__ xdbl,
    const float* __restrict__ xz,      // z rows E..2E-1
    const unsigned short* __restrict__ dt16,
    const float* __restrict__ Alog,
    const float* __restrict__ Dp,
    const float* __restrict__ hin,     // [NCH][4][1024][16]
    unsigned short* __restrict__ ybf,  // (4,2048,1024) bf16
    int rev)
{
    const int bx = blockIdx.x;
    const int c  = bx >> 8;
    const int j  = bx & 255;
    const int b  = j >> 6;
    const int e0 = (j & 63) << 4;
    const int tid = threadIdx.x;
    const int g = tid >> 4;
    const int n = tid & 15;
    const int e = e0 + g;

    __shared__ float sDt[16][68];
    __shared__ float sDu[16][68];
    __shared__ float sU[16][68];
    __shared__ float sB[16][68];
    __shared__ float sC[16][68];
    __shared__ float sP[16][17][20];
    __shared__ unsigned short sY[64][20];

    const float A_n = -__expf(Alog[(size_t)e * Ns + n]);
    const float Dv  = Dp[e];
    float h = hin[((size_t)(c * 4 + b) * 1024 + e) * 16 + n];

    const unsigned short* up  = xcE + ((size_t)b * Ei + e) * Lc;
    const float* zp  = xz + ((size_t)b * 2048 + Ei + e) * Lc;
    const unsigned short* dtp = dt16 + ((size_t)b * Ei + e) * Lc;
    const float* xdb = xdbl + (size_t)b * 64 * Lc;

    const int tbeg = c * TCH;
    for (int t0 = tbeg; t0 < tbeg + TCH; t0 += 64) {
        ushort4 uq4 = *(const ushort4*)&up[t0 + n * 4];
        float4 uq = make_float4(bf2f(uq4.x), bf2f(uq4.y), bf2f(uq4.z), bf2f(uq4.w));
        *(float4*)&sU[g][n * 4] = uq;
        ushort4 dq = *(const ushort4*)&dtp[t0 + n * 4];
        float4 dtq = make_float4(bf2f(dq.x), bf2f(dq.y), bf2f(dq.z), bf2f(dq.w));
        *(float4*)&sDt[g][n * 4] = dtq;
        *(float4*)&sDu[g][n * 4] =
            make_float4(dtq.x * uq.x, dtq.y * uq.y, dtq.z * uq.z, dtq.w * uq.w);
        *(float4*)&sB[g][n * 4] = *(const float4*)&xdb[(size_t)(32 + g) * Lc + t0 + n * 4];
        *(float4*)&sC[g][n * 4] = *(const float4*)&xdb[(size_t)(48 + g) * Lc + t0 + n * 4];
        __syncthreads();

#pragma unroll
        for (int s = 0; s < 4; s++) {
#pragma unroll
            for (int t2 = 0; t2 < 16; t2++) {
                int tt = s * 16 + t2;
                float dA = __expf(sDt[g][tt] * A_n);
                h = fmaf(dA, h, sDu[g][tt] * sB[n][tt]);
                sP[g][t2][n] = h * sC[n][tt];
            }
            // same-wave transposed reduce: lane (g,n) sums states for tt = s*16+n
            float4 p0 = *(float4*)&sP[g][n][0];
            float4 p1 = *(float4*)&sP[g][n][4];
            float4 p2 = *(float4*)&sP[g][n][8];
            float4 p3 = *(float4*)&sP[g][n][12];
            float acc = ((p0.x + p0.y) + (p0.z + p0.w)) + ((p1.x + p1.y) + (p1.z + p1.w)) +
                        ((p2.x + p2.y) + (p2.z + p2.w)) + ((p3.x + p3.y) + (p3.z + p3.w));
            int tt = s * 16 + n;
            int t  = t0 + tt;
            int gi = rev ? (Lc - 1 - t) : t;
            float val = (acc + Dv * sU[g][tt]) * siluf(zp[gi]);
            sY[rev ? (63 - tt) : tt][g] = f2bf(val);
        }
        __syncthreads();

        // coalesced tile write: rows are contiguous t (fwd) or reversed range
        {
            int row = tid >> 2;
            int c4  = (tid & 3) * 4;
            int trow = rev ? (Lc - 64 - t0 + row) : (t0 + row);
            size_t gidx = ((size_t)b * Lc + trow) * Ei + e0 + c4;
            ushort4 tv = *(ushort4*)&sY[row][c4];
            if (rev) {
                ushort4 ov = *(ushort4*)&ybf[gidx];
                tv.x = f2bf(bf2f(tv.x) + bf2f(ov.x));
                tv.y = f2bf(bf2f(tv.y) + bf2f(ov.y));
                tv.z = f2bf(bf2f(tv.z) + bf2f(ov.z));
                tv.w = f2bf(bf2f(tv.w) + bf2f(ov.w));
            }
            *(ushort4*)&ybf[gidx] = tv;
        }
        __syncthreads();
    }
}

// ---------------------------------------------------------------------------
// K6: out_proj bf16 MFMA GEMM. out[b][n][m] = sum_e Wout[m][e]*ybf[b][n][e]
// ---------------------------------------------------------------------------
__global__ __launch_bounds__(256) void k_mfma_outproj(
    const unsigned short* __restrict__ Wbf,  // (512,1024) bf16
    const unsigned short* __restrict__ ybf,  // (4,2048,1024) bf16
    float* __restrict__ out)                 // (4,2048,512)
{
    const int b  = blockIdx.z;
    const int m0 = blockIdx.x * 64;
    const int n0 = blockIdx.y * 128;
    __shared__ __align__(16) unsigned short lA[64 * LDS_S];
    __shared__ __align__(16) unsigned short lB[128 * LDS_S];
    const int tid  = threadIdx.x;
    const int lane = tid & 63;
    const int w    = tid >> 6;
    const int wr   = w >> 1, wc = w & 1;

    f32x4 acc[2][4] = {};

    const unsigned short* yb = ybf + ((size_t)b * Lc + n0) * Ei;
    const unsigned short* Wb = Wbf + (size_t)m0 * Ei;

    for (int k0 = 0; k0 < Ei; k0 += 32) {
        {
            int c = tid;
            int row = c >> 2, col = (c & 3) * 8;
            *(uint4*)&lA[row * LDS_S + col] = *(const uint4*)&Wb[(size_t)row * Ei + k0 + col];
        }
#pragma unroll
        for (int i = 0; i < 2; i++) {
            int c = tid + i * 256;
            int row = c >> 2, col = (c & 3) * 8;
            *(uint4*)&lB[row * LDS_S + col] = *(const uint4*)&yb[(size_t)row * Ei + k0 + col];
        }
        __syncthreads();
        bf16x8 aF[2], bF[4];
#pragma unroll
        for (int f = 0; f < 2; f++)
            aF[f] = *(bf16x8*)&lA[(wr * 32 + f * 16 + (lane & 15)) * LDS_S + (lane >> 4) * 8];
#pragma unroll
        for (int f = 0; f < 4; f++)
            bF[f] = *(bf16x8*)&lB[(wc * 64 + f * 16 + (lane & 15)) * LDS_S + (lane >> 4) * 8];
#pragma unroll
        for (int i = 0; i < 2; i++)
#pragma unroll
            for (int j = 0; j < 4; j++)
                acc[i][j] = __builtin_amdgcn_mfma_f32_16x16x32_bf16(aF[i], bF[j], acc[i][j], 0, 0, 0);
        __syncthreads();
    }
    float* ob = out + (size_t)b * Lc * Dm;
#pragma unroll
    for (int i = 0; i < 2; i++) {
        int mm = m0 + wr * 32 + i * 16 + (lane >> 4) * 4;
#pragma unroll
        for (int j = 0; j < 4; j++) {
            int nn = n0 + wc * 64 + j * 16 + (lane & 15);
            *(f32x4*)&ob[(size_t)nn * Dm + mm] = acc[i][j];
        }
    }
}

// ---------------------------------------------------------------------------
// K7: fused residual add + RMSNorm (in place on d_out).
// ---------------------------------------------------------------------------
__global__ __launch_bounds__(256) void k_rms(float* __restrict__ out,
                                             const float* __restrict__ resid,
                                             const float* __restrict__ w) {
    int row  = blockIdx.x * 4 + (threadIdx.x >> 6);
    int lane = threadIdx.x & 63;
    float4* po = (float4*)(out + (size_t)row * Dm);
    const float4* pr = (const float4*)(resid + (size_t)row * Dm);
    const float4* pw = (const float4*)w;
    float4 a0 = po[lane], a1 = po[lane + 64];
    float4 r0 = pr[lane], r1 = pr[lane + 64];
    a0.x += r0.x; a0.y += r0.y; a0.z += r0.z; a0.w += r0.w;
    a1.x += r1.x; a1.y += r1.y; a1.z += r1.z; a1.w += r1.w;
    float q = a0.x * a0.x + a0.y * a0.y + a0.z * a0.z + a0.w * a0.w +
              a1.x * a1.x + a1.y * a1.y + a1.z * a1.z + a1.w * a1.w;
#pragma unroll
    for (int off = 32; off >= 1; off >>= 1) q += __shfl_xor(q, off);
    float scale = rsqrtf(q * (1.f / Dm) + EPSf);
    float4 w0 = pw[lane], w1 = pw[lane + 64];
    a0.x *= scale * w0.x; a0.y *= scale * w0.y; a0.z *= scale * w0.z; a0.w *= scale * w0.w;
    a1.x *= scale * w1.x; a1.y *= scale * w1.y; a1.z *= scale * w1.z; a1.w *= scale * w1.w;
    po[lane] = a0;
    po[lane + 64] = a1;
}

// ---------------------------------------------------------------------------
extern "C" void kernel_launch(void* const* d_in, const int* in_sizes, int n_in,
                              void* d_out, int out_size, void* d_ws, size_t ws_size,
                              hipStream_t stream) {
    const float* inp   = (const float*)d_in[0];
    const float* nw    = (const float*)d_in[1];
    const float* nbv   = (const float*)d_in[2];
    const float* Win   = (const float*)d_in[3];
    const float* cwf   = (const float*)d_in[4];
    const float* cbf   = (const float*)d_in[5];
    const float* xpwf  = (const float*)d_in[6];
    const float* dtwf  = (const float*)d_in[7];
    const float* dtbf  = (const float*)d_in[8];
    const float* Alogf = (const float*)d_in[9];
    const float* Df    = (const float*)d_in[10];
    const float* cwr   = (const float*)d_in[11];
    const float* cbr   = (const float*)d_in[12];
    const float* xpwr  = (const float*)d_in[13];
    const float* dtwr  = (const float*)d_in[14];
    const float* dtbr  = (const float*)d_in[15];
    const float* Alogr = (const float*)d_in[16];
    const float* Dr    = (const float*)d_in[17];
    const float* Wout  = (const float*)d_in[18];
    const float* nfw   = (const float*)d_in[19];
    float* outp = (float*)d_out;
    float* ws   = (float*)d_ws;

    // workspace layout (float units)
    float* xz   = ws;                                        // 16,777,216
    float* xdbl = xz + (size_t)16777216;                     //    524,288
    unsigned short* xcE = (unsigned short*)(xdbl + 524288);  // 8,388,608 us
    unsigned short* xcT = xcE + (size_t)8388608;             // 8,388,608 us
    unsigned short* ybf = xcT + (size_t)8388608;             // 8,388,608 us
    unsigned short* hbf = ybf + (size_t)8388608;             // 4,194,304 us
    unsigned short* wbi = hbf + (size_t)4194304;             // 1,048,576 us
    unsigned short* wbo = wbi + (size_t)1048576;             //   524,288 us
    unsigned short* dt16 = wbo + (size_t)524288;             // 8,388,608 us
    unsigned short* xpbf = dt16 + (size_t)8388608;           //    65,536 us
    unsigned short* xpbr = xpbf + (size_t)65536;             //    65,536 us

    // P/S/hin scratch lives in d_out (4.19M floats; overwritten by out_proj
    // at the end). Each buffer NCH*4*1024*16 = 1,048,576 floats.
    float* Pb   = outp;
    float* Sb   = outp + 1048576;
    float* hinb = outp + 2 * 1048576;

    k_ln<<<2048, 256, 0, stream>>>(inp, nw, nbv, hbf);
    k_cast<<<1024, 256, 0, stream>>>(Win, wbi);     // 2048*512
    k_cast<<<512, 256, 0, stream>>>(Wout, wbo);     // 512*1024
    k_cast<<<64, 256, 0, stream>>>(xpwf, xpbf);     // 64*1024
    k_cast<<<64, 256, 0, stream>>>(xpwr, xpbr);     // 64*1024
    k_mfma_inproj<<<dim3(16, 16, 4), 256, 0, stream>>>(wbi, hbf, xz);

    // forward branch
    k_conv<<<dim3(32, 64, 4), 256, 0, stream>>>(xz, cwf, cbf, xcE, xcT, 0);
    k_mfma_xdbl<<<dim3(16, 4), 256, 0, stream>>>(xpbf, xcT, xdbl);
    k_dt<<<dim3(32, 64, 4), 256, 0, stream>>>(xdbl, dtwf, dtbf, dt16);
    k_scan_p1<<<NCH * 256, 256, 0, stream>>>(xcE, xdbl, dt16, Alogf, Pb, Sb);
    k_scan_mid<<<256, 256, 0, stream>>>(Pb, Sb, hinb);
    k_scan_p2<<<NCH * 256, 256, 0, stream>>>(xcE, xdbl, xz, dt16, Alogf, Df, hinb, ybf, 0);

    // reverse branch (index-reversed, accumulates into ybf)
    k_conv<<<dim3(32, 64, 4), 256, 0, stream>>>(xz, cwr, cbr, xcE, xcT, 1);
    k_mfma_xdbl<<<dim3(16, 4), 256, 0, stream>>>(xpbr, xcT, xdbl);
    k_dt<<<dim3(32, 64, 4), 256, 0, stream>>>(xdbl, dtwr, dtbr, dt16);
    k_scan_p1<<<NCH * 256, 256, 0, stream>>>(xcE, xdbl, dt16, Alogr, Pb, Sb);
    k_scan_mid<<<256, 256, 0, stream>>>(Pb, Sb, hinb);
    k_scan_p2<<<NCH * 256, 256, 0, stream>>>(xcE, xdbl, xz, dt16, Alogr, Dr, hinb, ybf, 1);

    k_mfma_outproj<<<dim3(8, 16, 4), 256, 0, stream>>>(wbo, ybf, outp);
    k_rms<<<2048, 256, 0, stream>>>(outp, inp, nfw);
}